// Round 12
// baseline (376.580 us; speedup 1.0000x reference)
//
#include <hip/hip_runtime.h>

// Problem: B=4, C=64, H=W=256, D=16, C4=256, P=8.  HW=65536.
// xn (NHWC f16, 32MB) in d_out[0:32MB); u1 b=0..2 in d_out[32MB+8MB*b);
// u1(3), y1, u2 in ws.  fftmix per batch in order (overlay hazard).
// Round 12: b1+b2 merged into one mega launch, role = blockIdx.x & 1
// (interleaved dispatch -> each CU holds ~2 b1 + 2 b2 blocks; b1 work
// fills b2's barrier/latency bubbles).  LDS = 36.9KB union.

typedef _Float16 f16;
typedef _Float16 f16x2 __attribute__((ext_vector_type(2)));
typedef _Float16 f16x4 __attribute__((ext_vector_type(4)));
typedef _Float16 f16x8 __attribute__((ext_vector_type(8)));
typedef float f32x4 __attribute__((ext_vector_type(4)));

__device__ __forceinline__ float dot2f(f16x2 a, f16x2 b, float c) {
#if __has_builtin(__builtin_amdgcn_fdot2)
  return __builtin_amdgcn_fdot2(a, b, c, false);
#else
  return c + (float)a.x * (float)b.x + (float)a.y * (float)b.y;
#endif
}

// Packed-f16 tanh-form GELU: x * sigmoid(1.5958x + 0.07136x^3).
__device__ __forceinline__ f16x2 gelu_pk(f16x2 x) {
  const f16x2 c1 = {(f16)1.5957691f, (f16)1.5957691f};
  const f16x2 c3 = {(f16)0.0713548f, (f16)0.0713548f};
  const f16x2 cl = {(f16)-1.4426950f, (f16)-1.4426950f};
  f16x2 x2 = x * x;
  f16x2 u = x * (c1 + c3 * x2);
  f16x2 a = cl * u;
  f16 t0, t1;
#if __has_builtin(__builtin_amdgcn_exp2h)
  t0 = __builtin_amdgcn_exp2h(a[0]);
  t1 = __builtin_amdgcn_exp2h(a[1]);
#else
  t0 = (f16)exp2f((float)a[0]);
  t1 = (f16)exp2f((float)a[1]);
#endif
  f16 d0 = (f16)1.0f + t0, d1 = (f16)1.0f + t1;
  f16 r0, r1;
#if __has_builtin(__builtin_amdgcn_rcph)
  r0 = __builtin_amdgcn_rcph(d0);
  r1 = __builtin_amdgcn_rcph(d1);
#else
  r0 = (f16)(1.0f / (float)d0);
  r1 = (f16)(1.0f / (float)d1);
#endif
  f16x2 r = {r0, r1};
  return x * r;
}

__device__ __forceinline__ f16x2 cvtpk(float a, float b) {
  return __builtin_bit_cast(f16x2, __builtin_amdgcn_cvt_pkrtz(a, b));
}

// ---------------------------------------------------------------------------
// preconv (blocks 0..265): f16 weight conversion.  kappa (blocks 266..297).
// ---------------------------------------------------------------------------
__global__ void preconv_kernel(const float* __restrict__ w0, const float* __restrict__ w1,
                               const float* __restrict__ w2, const float* __restrict__ w4,
                               const float* __restrict__ w3, const float* __restrict__ b3,
                               const float* __restrict__ fw1, const float* __restrict__ fw2,
                               f16* __restrict__ W0h, f16* __restrict__ W1h,
                               f16* __restrict__ W2h, f16* __restrict__ W4h,
                               f16* __restrict__ w3pk, f16* __restrict__ b3pk,
                               float* __restrict__ kap1, float* __restrict__ kap2) {
  __shared__ float Wt[4][64];
  __shared__ float ct[8];
  int blk = blockIdx.x, t = threadIdx.x;
  if (blk < 266) {
    int i = blk * 256 + t;
    if (i < 16384) W0h[i] = (f16)w0[i];
    else if (i < 32768) W1h[i - 16384] = (f16)w1[i - 16384];
    else if (i < 49152) W2h[i - 32768] = (f16)w2[i - 32768];
    else if (i < 65536) W4h[i - 49152] = (f16)w4[i - 49152];
    else if (i < 67840) {
      int j = i - 65536;               // [g][tap][k]: value = w3[(g*8+k)*9+tap]
      int g = j / 72, r = j % 72, tap = r >> 3, k = r & 7;
      w3pk[j] = (f16)w3[(g * 8 + k) * 9 + tap];
    } else if (i < 68096) {
      int k = i - 67840;
      b3pk[k] = (f16)b3[k];
    }
    return;
  }
  int sub = t >> 6, lane = t & 63;
  int unit = (blk - 266) * 4 + sub;    // 0..127
  int which = unit >> 6, c = unit & 63;
  const float* fw = which ? fw2 : fw1;
  float* kap = which ? kap2 : kap1;
  int a = lane >> 3, bb = lane & 7;
  if (t == 0) {
    const float r2 = 0.70710678118654752440f;
    ct[0] = 1.f; ct[1] = r2; ct[2] = 0.f; ct[3] = -r2;
    ct[4] = -1.f; ct[5] = -r2; ct[6] = 0.f; ct[7] = r2;
  }
  Wt[sub][lane] = (bb <= 4) ? fw[c * 40 + a * 5 + bb]
                            : fw[c * 40 + ((8 - a) & 7) * 5 + (8 - bb)];
  __syncthreads();
  float acc = 0.f;
  for (int u = 0; u < 8; ++u)
    for (int v = 0; v < 8; ++v)
      acc += Wt[sub][u * 8 + v] * ct[(u * a + v * bb) & 7];
  kap[c * 64 + lane] = acc * 0.015625f;
}

// ---------------------------------------------------------------------------
// LayerNorm.  x NCHW f32 -> xn NHWC f16.  grid (256, 4).
// ---------------------------------------------------------------------------
__global__ void __launch_bounds__(256) ln_kernel(const float* __restrict__ x,
                                                 const float* __restrict__ lnw,
                                                 const float* __restrict__ lnb,
                                                 f16* __restrict__ xn) {
  int b = blockIdx.y;
  int px = blockIdx.x * 256 + threadIdx.x;
  const float* xp = x + ((size_t)b << 22) + px;
  float v[64];
  float s = 0.f;
#pragma unroll
  for (int c = 0; c < 64; ++c) { v[c] = xp[(size_t)c << 16]; s += v[c]; }
  float mu = s * (1.f / 64.f), s2 = 0.f;
#pragma unroll
  for (int c = 0; c < 64; ++c) { float d = v[c] - mu; s2 += d * d; }
  float rstd = rsqrtf(s2 * (1.f / 64.f) + 1e-6f);
  f16* op = xn + (size_t)b * 4194304 + (size_t)px * 64;
#pragma unroll
  for (int g = 0; g < 8; ++g) {
    f16x8 pk;
#pragma unroll
    for (int j = 0; j < 8; ++j) {
      int c = g * 8 + j;
      pk[j] = (f16)((v[c] - mu) * rstd * lnw[c] + lnb[c]);
    }
    *(f16x8*)(op + g * 8) = pk;
  }
}

// ---------------------------------------------------------------------------
// 3x3 dense conv 16ci->16co on xn c<16 -> y1 NHWC f16.  grid (256, 4).
// ---------------------------------------------------------------------------
__global__ void __launch_bounds__(256) pconv_kernel(const f16* __restrict__ xn,
                                                    const float* __restrict__ pw,
                                                    const float* __restrict__ pb,
                                                    f16* __restrict__ y1) {
  __shared__ __align__(16) char halo[18 * 640];
  __shared__ f16 wpk[2304];                      // [co][tap][ci]
  __shared__ float pbs[16];
  int t = threadIdx.x, blk = blockIdx.x, b = blockIdx.y;
  const f16* xnb = xn + (size_t)b * 4194304;
  f16* y1b = y1 + (size_t)b * 1048576;
  int h0 = (blk >> 4) << 4, w0 = (blk & 15) << 4;
  for (int i = t; i < 2304; i += 256) {
    int co = i / 144, r = i % 144, tap = r >> 4, ci = r & 15;
    wpk[i] = (f16)pw[co * 144 + ci * 9 + tap];
  }
  if (t < 16) pbs[t] = pb[t];
  for (int i = 0; i < 3; ++i) {
    int u = i * 256 + t;
    if (u < 648) {
      int hp = u >> 1, half = u & 1;
      int hr = hp / 18, hc = hp - hr * 18;
      int h = h0 - 1 + hr, w = w0 - 1 + hc;
      f16x8 v = {0, 0, 0, 0, 0, 0, 0, 0};
      if ((unsigned)h < 256u && (unsigned)w < 256u)
        v = *(const f16x8*)(xnb + ((((size_t)h << 8)) + w) * 64 + half * 8);
      *(f16x8*)(halo + hr * 640 + ((hc * 32 + half * 16) ^ ((hr & 7) << 4))) = v;
    }
  }
  __syncthreads();
  int rl = t >> 4, cl = t & 15;
  float acc[16];
#pragma unroll
  for (int co = 0; co < 16; ++co) acc[co] = pbs[co];
#pragma unroll
  for (int ty = 0; ty < 3; ++ty)
#pragma unroll
    for (int tx = 0; tx < 3; ++tx) {
      int hr = rl + ty, hc = cl + tx, tap = ty * 3 + tx;
      f16x8 ld0 = *(const f16x8*)(halo + hr * 640 + ((hc * 32) ^ ((hr & 7) << 4)));
      f16x8 ld1 = *(const f16x8*)(halo + hr * 640 + ((hc * 32 + 16) ^ ((hr & 7) << 4)));
#pragma unroll
      for (int co = 0; co < 16; ++co) {
#pragma unroll
        for (int p = 0; p < 4; ++p) {
          f16x2 xp = {ld0[2 * p], ld0[2 * p + 1]};
          f16x2 wp = *(const f16x2*)&wpk[co * 144 + tap * 16 + 2 * p];
          acc[co] = dot2f(xp, wp, acc[co]);
        }
#pragma unroll
        for (int p = 0; p < 4; ++p) {
          f16x2 xp = {ld1[2 * p], ld1[2 * p + 1]};
          f16x2 wp = *(const f16x2*)&wpk[co * 144 + tap * 16 + 8 + 2 * p];
          acc[co] = dot2f(xp, wp, acc[co]);
        }
      }
    }
  size_t px = (((size_t)(h0 + rl)) << 8) + w0 + cl;
  f16x8 o0, o1;
#pragma unroll
  for (int j = 0; j < 8; ++j) { o0[j] = (f16)acc[j]; o1[j] = (f16)acc[8 + j]; }
  *(f16x8*)(y1b + px * 16) = o0;
  *(f16x8*)(y1b + px * 16 + 8) = o1;
}

// ---------------------------------------------------------------------------
// Branch-1 body (round-11 b1, unchanged numerics).  smem: As@0, Es@16384.
// ---------------------------------------------------------------------------
__device__ __forceinline__ void b1_body(
    char* smem, int sub, int b, const f16* __restrict__ xn,
    const f16* __restrict__ W0h, const float* __restrict__ b0,
    const f16* __restrict__ W2h, const float* __restrict__ b2,
    f16* __restrict__ u1d, f16* __restrict__ u1w) {
  f16* As = (f16*)smem;
  f16* Es = (f16*)(smem + 16384);
  int t = threadIdx.x;
  const f16* xnb = xn + (size_t)b * 4194304;
  f16* u1b = (b < 3) ? (u1d + (size_t)b * 4194304) : u1w;
  int px0 = sub << 7;
#pragma unroll
  for (int i = 0; i < 4; ++i) {
    int u = i * 256 + t, row = u >> 3, cb = (u & 7) << 4;
    f16x8 v = *(const f16x8*)(xnb + (size_t)(px0 + row) * 64 + (cb >> 1));
    *(f16x8*)((char*)As + row * 128 + (cb ^ ((row & 7) << 4))) = v;
  }
  __syncthreads();
  int l = t & 63, wv = t >> 6, lm = l & 15, kg = l >> 4;
  f32x4 uacc[2][4];
#pragma unroll
  for (int a = 0; a < 2; ++a)
#pragma unroll
    for (int n = 0; n < 4; ++n) uacc[a][n] = (f32x4){0.f, 0.f, 0.f, 0.f};
  for (int cc = 0; cc < 4; ++cc) {
    f32x4 eacc[2][4];
#pragma unroll
    for (int a = 0; a < 2; ++a)
#pragma unroll
      for (int n = 0; n < 4; ++n) eacc[a][n] = (f32x4){0.f, 0.f, 0.f, 0.f};
#pragma unroll
    for (int kk = 0; kk < 2; ++kk) {
      int kb = kk * 64 + kg * 16;
      f16x8 af[2];
#pragma unroll
      for (int mt = 0; mt < 2; ++mt) {
        int row = wv * 32 + mt * 16 + lm;
        af[mt] = *(const f16x8*)((char*)As + row * 128 + (kb ^ ((row & 7) << 4)));
      }
      f16x8 bf[4];
#pragma unroll
      for (int nt = 0; nt < 4; ++nt) {
        int co = cc * 64 + nt * 16 + lm;
        bf[nt] = *(const f16x8*)(W0h + (size_t)co * 64 + kk * 32 + kg * 8);
      }
#pragma unroll
      for (int mt = 0; mt < 2; ++mt)
#pragma unroll
        for (int nt = 0; nt < 4; ++nt)
          eacc[mt][nt] = __builtin_amdgcn_mfma_f32_16x16x32_f16(bf[nt], af[mt], eacc[mt][nt], 0, 0, 0);
    }
    if (cc) __syncthreads();
#pragma unroll
    for (int mt = 0; mt < 2; ++mt) {
      int row = wv * 32 + mt * 16 + lm;
#pragma unroll
      for (int nt = 0; nt < 4; ++nt) {
        int c0 = nt * 16 + kg * 4;
        float4 bz4 = *(const float4*)&b0[cc * 64 + c0];
        f16x2 lo = gelu_pk(cvtpk(eacc[mt][nt][0] + bz4.x, eacc[mt][nt][1] + bz4.y));
        f16x2 hi = gelu_pk(cvtpk(eacc[mt][nt][2] + bz4.z, eacc[mt][nt][3] + bz4.w));
        f16x4 pk = {lo[0], lo[1], hi[0], hi[1]};
        *(f16x4*)((char*)Es + row * 128 + ((c0 * 2) ^ ((row & 7) << 4))) = pk;
      }
    }
    __syncthreads();
#pragma unroll
    for (int kk = 0; kk < 2; ++kk) {
      int kb = kk * 64 + kg * 16;
      f16x8 af[2];
#pragma unroll
      for (int mt = 0; mt < 2; ++mt) {
        int row = wv * 32 + mt * 16 + lm;
        af[mt] = *(const f16x8*)((char*)Es + row * 128 + (kb ^ ((row & 7) << 4)));
      }
      f16x8 bf[4];
#pragma unroll
      for (int nt = 0; nt < 4; ++nt) {
        int co = nt * 16 + lm;
        bf[nt] = *(const f16x8*)(W2h + (size_t)co * 256 + cc * 64 + kk * 32 + kg * 8);
      }
#pragma unroll
      for (int mt = 0; mt < 2; ++mt)
#pragma unroll
        for (int nt = 0; nt < 4; ++nt)
          uacc[mt][nt] = __builtin_amdgcn_mfma_f32_16x16x32_f16(bf[nt], af[mt], uacc[mt][nt], 0, 0, 0);
    }
    __syncthreads();
  }
#pragma unroll
  for (int mt = 0; mt < 2; ++mt) {
    int row = wv * 32 + mt * 16 + lm;
#pragma unroll
    for (int nt = 0; nt < 4; ++nt) {
      int c0 = nt * 16 + kg * 4;
      float4 bz4 = *(const float4*)&b2[c0];
      f16x2 lo = cvtpk(uacc[mt][nt][0] + bz4.x, uacc[mt][nt][1] + bz4.y);
      f16x2 hi = cvtpk(uacc[mt][nt][2] + bz4.z, uacc[mt][nt][3] + bz4.w);
      f16x4 pk = {lo[0], lo[1], hi[0], hi[1]};
      *(f16x4*)((char*)Es + row * 128 + ((c0 * 2) ^ ((row & 7) << 4))) = pk;
    }
  }
  __syncthreads();
  int co = t >> 2, q = t & 3;
  f16x8 o[4];
#pragma unroll
  for (int i = 0; i < 32; ++i) {
    int m = q * 32 + i;
    o[i >> 3][i & 7] =
        *(const f16*)((char*)Es + m * 128 + ((co * 2) ^ ((m & 7) << 4)));
  }
  f16* up = u1b + ((size_t)co << 16) + px0 + q * 32;
#pragma unroll
  for (int ss = 0; ss < 4; ++ss) *(f16x8*)(up + ss * 8) = o[ss];
}

// ---------------------------------------------------------------------------
// Branch-2 body (round-11 b2, unchanged numerics).  smem: xin@0, Es@24576.
// ---------------------------------------------------------------------------
__device__ __forceinline__ void b2_body(
    char* smem, int sub, int b, const f16* __restrict__ xn,
    const f16* __restrict__ y1, const f16* __restrict__ W1h,
    const float* __restrict__ b1v, const f16* __restrict__ W4h,
    const float* __restrict__ b4, const f16* __restrict__ w3pk,
    const f16* __restrict__ b3pk, f16* __restrict__ u2) {
  f16* xin = (f16*)smem;                    // 192 rows x 128B
  f16* Es = (f16*)(smem + 24576);           // 192 rows x 64B
  int t = threadIdx.x;
  const f16* xnb = xn + (size_t)b * 4194304;
  const f16* y1b = y1 + (size_t)b * 1048576;
  f16* u2b = u2 + (size_t)b * 4194304;
  int h0 = (sub >> 4) << 3, w0 = (sub & 15) << 4;
#pragma unroll
  for (int i = 0; i < 6; ++i) {
    int u = i * 256 + t;                 // 0..1535 = 192 rows x 8 parts
    int hp = u >> 3, part = u & 7;
    f16x8 v = {0, 0, 0, 0, 0, 0, 0, 0};
    if (hp < 180) {
      int hr = hp / 18, hc = hp - hr * 18;
      int h = h0 - 1 + hr, w = w0 - 1 + hc;
      if ((unsigned)h < 256u && (unsigned)w < 256u) {
        size_t px = ((size_t)h << 8) + w;
        v = (part < 2) ? *(const f16x8*)(y1b + px * 16 + part * 8)
                       : *(const f16x8*)(xnb + px * 64 + part * 8);
      }
    }
    *(f16x8*)((char*)xin + hp * 128 + ((part * 16) ^ ((hp & 7) << 4))) = v;
  }
  __syncthreads();
  int l = t & 63, wv = t >> 6, lm = l & 15, kg = l >> 4;
  f32x4 uacc[2][4];
#pragma unroll
  for (int a = 0; a < 2; ++a)
#pragma unroll
    for (int n = 0; n < 4; ++n) uacc[a][n] = (f32x4){0.f, 0.f, 0.f, 0.f};
  for (int kc = 0; kc < 4; ++kc) {
#pragma unroll
    for (int sb = 0; sb < 2; ++sb) {
      int ce0 = kc * 64 + sb * 32;
      f32x4 eacc[3][2];
#pragma unroll
      for (int a = 0; a < 3; ++a)
#pragma unroll
        for (int n = 0; n < 2; ++n) eacc[a][n] = (f32x4){0.f, 0.f, 0.f, 0.f};
#pragma unroll
      for (int kk = 0; kk < 2; ++kk) {
        int kb = kk * 64 + kg * 16;
        f16x8 af[3];
#pragma unroll
        for (int mtl = 0; mtl < 3; ++mtl) {
          int row = (mtl * 4 + wv) * 16 + lm;
          af[mtl] = *(const f16x8*)((char*)xin + row * 128 + (kb ^ ((row & 7) << 4)));
        }
        f16x8 bf[2];
#pragma unroll
        for (int nt = 0; nt < 2; ++nt) {
          int ce = ce0 + nt * 16 + lm;
          bf[nt] = *(const f16x8*)(W1h + (size_t)ce * 64 + kk * 32 + kg * 8);
        }
#pragma unroll
        for (int mtl = 0; mtl < 3; ++mtl)
#pragma unroll
          for (int nt = 0; nt < 2; ++nt)
            eacc[mtl][nt] = __builtin_amdgcn_mfma_f32_16x16x32_f16(bf[nt], af[mtl], eacc[mtl][nt], 0, 0, 0);
      }
      __syncthreads();   // prior sub's dw reads of Es complete
#pragma unroll
      for (int mtl = 0; mtl < 3; ++mtl) {
        int row = (mtl * 4 + wv) * 16 + lm;
#pragma unroll
        for (int nt = 0; nt < 2; ++nt) {
          int cL = nt * 16 + kg * 4;
          float4 bz4 = *(const float4*)&b1v[ce0 + cL];
          f16x2 lo = gelu_pk(cvtpk(eacc[mtl][nt][0] + bz4.x, eacc[mtl][nt][1] + bz4.y));
          f16x2 hi = gelu_pk(cvtpk(eacc[mtl][nt][2] + bz4.z, eacc[mtl][nt][3] + bz4.w));
          f16x4 pk = {lo[0], lo[1], hi[0], hi[1]};
          *(f16x4*)((char*)Es + row * 64 + ((cL * 2) ^ (((row >> 1) & 3) << 4))) = pk;
        }
      }
      __syncthreads();   // Es visible to all
      int g9 = (ce0 + kg * 8) >> 3;
      f16x8 wv9[9];
#pragma unroll
      for (int tap = 0; tap < 9; ++tap)
        wv9[tap] = *(const f16x8*)(w3pk + g9 * 72 + tap * 8);
      f16x8 bias8 = *(const f16x8*)(b3pk + ce0 + kg * 8);
      f16x8 af2[2];
#pragma unroll
      for (int mt = 0; mt < 2; ++mt) {
        int px = wv * 32 + mt * 16 + lm;
        int rl2 = px >> 4, cl2 = px & 15;
        f16x8 a8 = bias8;
#pragma unroll
        for (int ty = 0; ty < 3; ++ty)
#pragma unroll
          for (int tx = 0; tx < 3; ++tx) {
            int hp = (rl2 + ty) * 18 + (cl2 + tx);
            f16x8 xv = *(const f16x8*)((char*)Es + hp * 64 + ((kg * 16) ^ (((hp >> 1) & 3) << 4)));
            a8 += xv * wv9[ty * 3 + tx];
          }
#pragma unroll
        for (int j2 = 0; j2 < 4; ++j2) {
          f16x2 g = gelu_pk((f16x2){a8[2 * j2], a8[2 * j2 + 1]});
          af2[mt][2 * j2] = g[0];
          af2[mt][2 * j2 + 1] = g[1];
        }
      }
      f16x8 bf2[4];
#pragma unroll
      for (int nt = 0; nt < 4; ++nt) {
        int co = nt * 16 + lm;
        bf2[nt] = *(const f16x8*)(W4h + (size_t)co * 256 + ce0 + kg * 8);
      }
#pragma unroll
      for (int mt = 0; mt < 2; ++mt)
#pragma unroll
        for (int nt = 0; nt < 4; ++nt)
          uacc[mt][nt] = __builtin_amdgcn_mfma_f32_16x16x32_f16(bf2[nt], af2[mt], uacc[mt][nt], 0, 0, 0);
    }
  }
  __syncthreads();   // all xin reads done before epilogue reuse
#pragma unroll
  for (int mt = 0; mt < 2; ++mt) {
    int m = wv * 32 + mt * 16 + lm;
#pragma unroll
    for (int nt = 0; nt < 4; ++nt) {
      int c0 = nt * 16 + kg * 4;
      float4 bz4 = *(const float4*)&b4[c0];
      f16x2 lo = cvtpk(uacc[mt][nt][0] + bz4.x, uacc[mt][nt][1] + bz4.y);
      f16x2 hi = cvtpk(uacc[mt][nt][2] + bz4.z, uacc[mt][nt][3] + bz4.w);
      f16x4 pk = {lo[0], lo[1], hi[0], hi[1]};
      *(f16x4*)((char*)xin + m * 128 + ((c0 * 2) ^ ((m & 7) << 4))) = pk;
    }
  }
  __syncthreads();
  int co = t >> 2, q = t & 3;
  f16x8 o[4];
#pragma unroll
  for (int i = 0; i < 32; ++i) {
    int m = q * 32 + i;
    o[i >> 3][i & 7] =
        *(const f16*)((char*)xin + m * 128 + ((co * 2) ^ ((m & 7) << 4)));
  }
  f16* up = u2b + ((size_t)co << 16) + (size_t)(h0 + 2 * q) * 256 + w0;
  *(f16x8*)(up) = o[0];
  *(f16x8*)(up + 8) = o[1];
  *(f16x8*)(up + 256) = o[2];
  *(f16x8*)(up + 256 + 8) = o[3];
}

// ---------------------------------------------------------------------------
// Mega kernel: role-interleaved b1/b2.  grid (1024, 4); role = x & 1,
// sub = x >> 1.  LDS = 36864-byte union (4 blocks/CU).
// ---------------------------------------------------------------------------
__global__ void __launch_bounds__(256) mega_kernel(
    const f16* __restrict__ xn, const f16* __restrict__ y1,
    const f16* __restrict__ W0h, const float* __restrict__ b0,
    const f16* __restrict__ W2h, const float* __restrict__ b2,
    const f16* __restrict__ W1h, const float* __restrict__ b1v,
    const f16* __restrict__ W4h, const float* __restrict__ b4,
    const f16* __restrict__ w3pk, const f16* __restrict__ b3pk,
    f16* __restrict__ u1d, f16* __restrict__ u1w, f16* __restrict__ u2) {
  __shared__ __align__(16) char smem[36864];
  int sub = blockIdx.x >> 1, b = blockIdx.y;
  if (blockIdx.x & 1)
    b2_body(smem, sub, b, xn, y1, W1h, b1v, W4h, b4, w3pk, b3pk, u2);
  else
    b1_body(smem, sub, b, xn, W0h, b0, W2h, b2, u1d, u1w);
}

// ---------------------------------------------------------------------------
// out(b) = circconv8x8(u1,k1) + circconv8x8(u2,k2).  Per batch, grid 1024.
// ---------------------------------------------------------------------------
__global__ void __launch_bounds__(256) fftmix_kernel(
    const f16* __restrict__ u1, const f16* __restrict__ u2,
    const float* __restrict__ kap1, const float* __restrict__ kap2,
    float* __restrict__ out, int b) {
  int blk = blockIdx.x;
  int c = blk >> 4, part = blk & 15;
  int t = threadIdx.x;
  int l = t & 63, wv = (t >> 6) & 3;
  int s = l >> 3, tq = l & 7;
  __shared__ unsigned int kls[64];
  if (t < 64) {
    f16 k1 = (f16)kap1[(c << 6) + t];
    f16 k2 = (f16)kap2[(c << 6) + t];
    kls[t] = (unsigned int)__builtin_bit_cast(unsigned short, k1) |
             ((unsigned int)__builtin_bit_cast(unsigned short, k2) << 16);
  }
  __syncthreads();
  unsigned int kp[64];
#pragma unroll
  for (int j = 0; j < 64; ++j) {
    int idx = (((s - (j >> 3)) & 7) << 3) | ((tq - (j & 7)) & 7);
    kp[j] = kls[idx];
  }
  size_t cb = ((size_t)c) << 16;
  size_t obase = ((size_t)(b * 64 + c)) << 16;
  int win0 = part * 64 + wv * 16;
  for (int it = 0; it < 16; ++it) {
    int win = win0 + it;
    int wh = win >> 5, ww = win & 31;
    size_t pix = (size_t)((wh * 8 + s) << 8) + ww * 8 + tq;
    unsigned int pk =
        (unsigned int)__builtin_bit_cast(unsigned short, u1[cb + pix]) |
        ((unsigned int)__builtin_bit_cast(unsigned short, u2[cb + pix]) << 16);
    float ac0 = 0.f, ac1 = 0.f, ac2 = 0.f, ac3 = 0.f;
#pragma unroll
    for (int j = 0; j < 64; j += 4) {
      unsigned int v0 = (unsigned int)__builtin_amdgcn_readlane((int)pk, j);
      unsigned int v1 = (unsigned int)__builtin_amdgcn_readlane((int)pk, j + 1);
      unsigned int v2 = (unsigned int)__builtin_amdgcn_readlane((int)pk, j + 2);
      unsigned int v3 = (unsigned int)__builtin_amdgcn_readlane((int)pk, j + 3);
      ac0 = dot2f(__builtin_bit_cast(f16x2, v0), __builtin_bit_cast(f16x2, kp[j]), ac0);
      ac1 = dot2f(__builtin_bit_cast(f16x2, v1), __builtin_bit_cast(f16x2, kp[j + 1]), ac1);
      ac2 = dot2f(__builtin_bit_cast(f16x2, v2), __builtin_bit_cast(f16x2, kp[j + 2]), ac2);
      ac3 = dot2f(__builtin_bit_cast(f16x2, v3), __builtin_bit_cast(f16x2, kp[j + 3]), ac3);
    }
    out[obase + pix] = (ac0 + ac1) + (ac2 + ac3);
  }
}

// ---------------------------------------------------------------------------
__global__ void diag_kernel(float* __restrict__ out, float code, int n) {
  int i = blockIdx.x * 256 + threadIdx.x;
  for (int p = i; p < n; p += 256 * 4096) out[p] = (p == 0) ? code : 0.f;
}

// ---------------------------------------------------------------------------
extern "C" void kernel_launch(void* const* d_in, const int* in_sizes, int n_in,
                              void* d_out, int out_size, void* d_ws,
                              size_t ws_size, hipStream_t stream) {
  const float* x       = (const float*)d_in[0];
  const float* ln_w    = (const float*)d_in[1];
  const float* ln_b    = (const float*)d_in[2];
  const float* pconv_w = (const float*)d_in[3];
  const float* pconv_b = (const float*)d_in[4];
  const float* w0      = (const float*)d_in[5];
  const float* b0      = (const float*)d_in[6];
  const float* w1      = (const float*)d_in[7];
  const float* b1      = (const float*)d_in[8];
  const float* w2      = (const float*)d_in[9];
  const float* b2      = (const float*)d_in[10];
  const float* w3      = (const float*)d_in[11];
  const float* b3      = (const float*)d_in[12];
  const float* w4      = (const float*)d_in[13];
  const float* b4      = (const float*)d_in[14];
  const float* fftw1   = (const float*)d_in[15];
  const float* fftw2   = (const float*)d_in[16];

  const size_t OFF_KAP1 = 0;                        // f32 [64][64] = 16 KB
  const size_t OFF_KAP2 = 16384;
  const size_t OFF_W0H  = 32768;                    // 32 KB each
  const size_t OFF_W1H  = 65536;
  const size_t OFF_W2H  = 98304;
  const size_t OFF_W4H  = 131072;
  const size_t OFF_W3PK = 163840;                   // 4608 B
  const size_t OFF_B3PK = 168448;                   // 512 B
  const size_t OFF_Y1   = 168960;                   // f16 4 x [65536][16] = 8 MB
  const size_t OFF_U2   = OFF_Y1 + 8388608ull;      // f16 4 x [64][65536] = 32 MB
  const size_t OFF_U13  = OFF_U2 + 33554432ull;     // f16 [64][65536] = 8 MB (b=3)
  const size_t WS_NEED  = OFF_U13 + 8388608ull;     // 50,500,608 B (proven fits)

  float* outF = (float*)d_out;
  if (ws_size < WS_NEED) {
    diag_kernel<<<4096, 256, 0, stream>>>(outF, 1000.0f + (float)(ws_size >> 20), 16777216);
    return;
  }
  char* ws = (char*)d_ws;
  float* kap1 = (float*)(ws + OFF_KAP1);
  float* kap2 = (float*)(ws + OFF_KAP2);
  f16* W0h  = (f16*)(ws + OFF_W0H);
  f16* W1h  = (f16*)(ws + OFF_W1H);
  f16* W2h  = (f16*)(ws + OFF_W2H);
  f16* W4h  = (f16*)(ws + OFF_W4H);
  f16* w3pk = (f16*)(ws + OFF_W3PK);
  f16* b3pk = (f16*)(ws + OFF_B3PK);
  f16* Y1   = (f16*)(ws + OFF_Y1);
  f16* U2   = (f16*)(ws + OFF_U2);
  f16* U13  = (f16*)(ws + OFF_U13);

  // d_out overlay: xn = f16[0:32MB); u1(b<3) = f16[32MB + 8MB*b)
  f16* XN  = (f16*)d_out;
  f16* U1D = (f16*)d_out + 16777216;

  preconv_kernel<<<298, 256, 0, stream>>>(w0, w1, w2, w4, w3, b3, fftw1, fftw2,
                                          W0h, W1h, W2h, W4h, w3pk, b3pk,
                                          kap1, kap2);
  ln_kernel<<<dim3(256, 4), 256, 0, stream>>>(x, ln_w, ln_b, XN);
  pconv_kernel<<<dim3(256, 4), 256, 0, stream>>>(XN, pconv_w, pconv_b, Y1);
  mega_kernel<<<dim3(1024, 4), 256, 0, stream>>>(XN, Y1, W0h, b0, W2h, b2,
                                                 W1h, b1, W4h, b4, w3pk, b3pk,
                                                 U1D, U13, U2);
  for (int b = 0; b < 4; ++b) {
    const f16* u1b = (b < 3) ? (U1D + (size_t)b * 4194304) : U13;
    fftmix_kernel<<<1024, 256, 0, stream>>>(u1b, U2 + (size_t)b * 4194304,
                                            kap1, kap2, outF, b);
  }
}

// Round 13
// 336.059 us; speedup vs baseline: 1.1206x; 1.1206x over previous
//
#include <hip/hip_runtime.h>

// Problem: B=4, C=64, H=W=256, D=16, C4=256, P=8.  HW=65536.
// xn (NHWC f16, 32MB) in d_out[0:32MB); u1 b=0..2 in d_out[32MB+8MB*b);
// u1(3), y1, u2 in ws.  fftmix batches {0,1} then {2} then {3} (overlay).
// Round 13: revert r12 merge; b2 expand pipelined ahead of dw (same math);
// preconv folded into ln launch; pconv folded into b1 launch (no LDS union
// penalty: pconv 16.2KB < b1 32KB); fftmix {0,1} combined.  6 launches.

typedef _Float16 f16;
typedef _Float16 f16x2 __attribute__((ext_vector_type(2)));
typedef _Float16 f16x4 __attribute__((ext_vector_type(4)));
typedef _Float16 f16x8 __attribute__((ext_vector_type(8)));
typedef float f32x4 __attribute__((ext_vector_type(4)));

__device__ __forceinline__ float dot2f(f16x2 a, f16x2 b, float c) {
#if __has_builtin(__builtin_amdgcn_fdot2)
  return __builtin_amdgcn_fdot2(a, b, c, false);
#else
  return c + (float)a.x * (float)b.x + (float)a.y * (float)b.y;
#endif
}

// Packed-f16 tanh-form GELU: x * sigmoid(1.5958x + 0.07136x^3).
__device__ __forceinline__ f16x2 gelu_pk(f16x2 x) {
  const f16x2 c1 = {(f16)1.5957691f, (f16)1.5957691f};
  const f16x2 c3 = {(f16)0.0713548f, (f16)0.0713548f};
  const f16x2 cl = {(f16)-1.4426950f, (f16)-1.4426950f};
  f16x2 x2 = x * x;
  f16x2 u = x * (c1 + c3 * x2);
  f16x2 a = cl * u;
  f16 t0, t1;
#if __has_builtin(__builtin_amdgcn_exp2h)
  t0 = __builtin_amdgcn_exp2h(a[0]);
  t1 = __builtin_amdgcn_exp2h(a[1]);
#else
  t0 = (f16)exp2f((float)a[0]);
  t1 = (f16)exp2f((float)a[1]);
#endif
  f16 d0 = (f16)1.0f + t0, d1 = (f16)1.0f + t1;
  f16 r0, r1;
#if __has_builtin(__builtin_amdgcn_rcph)
  r0 = __builtin_amdgcn_rcph(d0);
  r1 = __builtin_amdgcn_rcph(d1);
#else
  r0 = (f16)(1.0f / (float)d0);
  r1 = (f16)(1.0f / (float)d1);
#endif
  f16x2 r = {r0, r1};
  return x * r;
}

__device__ __forceinline__ f16x2 cvtpk(float a, float b) {
  return __builtin_bit_cast(f16x2, __builtin_amdgcn_cvt_pkrtz(a, b));
}

// ---------------------------------------------------------------------------
// ln+preconv launch.  Blocks 0..1023: LayerNorm (b = x>>8).  Blocks
// 1024..1289: weight f16 conversion.  Blocks 1290..1321: kappa (4 units ea).
// ---------------------------------------------------------------------------
__global__ void __launch_bounds__(256) lnpre_kernel(
    const float* __restrict__ x, const float* __restrict__ lnw,
    const float* __restrict__ lnb, f16* __restrict__ xn,
    const float* __restrict__ w0, const float* __restrict__ w1,
    const float* __restrict__ w2, const float* __restrict__ w4,
    const float* __restrict__ w3, const float* __restrict__ b3,
    const float* __restrict__ fw1, const float* __restrict__ fw2,
    f16* __restrict__ W0h, f16* __restrict__ W1h,
    f16* __restrict__ W2h, f16* __restrict__ W4h,
    f16* __restrict__ w3pk, f16* __restrict__ b3pk,
    float* __restrict__ kap1, float* __restrict__ kap2) {
  __shared__ float Wt[4][64];
  __shared__ float ct[8];
  int blk = blockIdx.x, t = threadIdx.x;
  if (blk < 1024) {
    int b = blk >> 8;
    int px = (blk & 255) * 256 + t;
    const float* xp = x + ((size_t)b << 22) + px;
    float v[64];
    float s = 0.f;
#pragma unroll
    for (int c = 0; c < 64; ++c) { v[c] = xp[(size_t)c << 16]; s += v[c]; }
    float mu = s * (1.f / 64.f), s2 = 0.f;
#pragma unroll
    for (int c = 0; c < 64; ++c) { float d = v[c] - mu; s2 += d * d; }
    float rstd = rsqrtf(s2 * (1.f / 64.f) + 1e-6f);
    f16* op = xn + (size_t)b * 4194304 + (size_t)px * 64;
#pragma unroll
    for (int g = 0; g < 8; ++g) {
      f16x8 pk;
#pragma unroll
      for (int j = 0; j < 8; ++j) {
        int c = g * 8 + j;
        pk[j] = (f16)((v[c] - mu) * rstd * lnw[c] + lnb[c]);
      }
      *(f16x8*)(op + g * 8) = pk;
    }
    return;
  }
  if (blk < 1290) {
    int i = (blk - 1024) * 256 + t;
    if (i < 16384) W0h[i] = (f16)w0[i];
    else if (i < 32768) W1h[i - 16384] = (f16)w1[i - 16384];
    else if (i < 49152) W2h[i - 32768] = (f16)w2[i - 32768];
    else if (i < 65536) W4h[i - 49152] = (f16)w4[i - 49152];
    else if (i < 67840) {
      int j = i - 65536;               // [g][tap][k]: value = w3[(g*8+k)*9+tap]
      int g = j / 72, r = j % 72, tap = r >> 3, k = r & 7;
      w3pk[j] = (f16)w3[(g * 8 + k) * 9 + tap];
    } else if (i < 68096) {
      int k = i - 67840;
      b3pk[k] = (f16)b3[k];
    }
    return;
  }
  int sub = t >> 6, lane = t & 63;
  int unit = (blk - 1290) * 4 + sub;   // 0..127
  int which = unit >> 6, c = unit & 63;
  const float* fw = which ? fw2 : fw1;
  float* kap = which ? kap2 : kap1;
  int a = lane >> 3, bb = lane & 7;
  if (t == 0) {
    const float r2 = 0.70710678118654752440f;
    ct[0] = 1.f; ct[1] = r2; ct[2] = 0.f; ct[3] = -r2;
    ct[4] = -1.f; ct[5] = -r2; ct[6] = 0.f; ct[7] = r2;
  }
  Wt[sub][lane] = (bb <= 4) ? fw[c * 40 + a * 5 + bb]
                            : fw[c * 40 + ((8 - a) & 7) * 5 + (8 - bb)];
  __syncthreads();
  float acc = 0.f;
  for (int u = 0; u < 8; ++u)
    for (int v = 0; v < 8; ++v)
      acc += Wt[sub][u * 8 + v] * ct[(u * a + v * bb) & 7];
  kap[c * 64 + lane] = acc * 0.015625f;
}

// ---------------------------------------------------------------------------
// pconv body (3x3 dense conv 16ci->16co on xn c<16 -> y1 NHWC f16).
// ---------------------------------------------------------------------------
__device__ __forceinline__ void pconv_body(
    char* smem, int blk, int b, const f16* __restrict__ xn,
    const float* __restrict__ pw, const float* __restrict__ pb,
    f16* __restrict__ y1) {
  char* halo = smem;                          // 18 * 640 = 11520
  f16* wpk = (f16*)(smem + 11520);            // 2304 f16 = 4608
  float* pbs = (float*)(smem + 16128);        // 64
  int t = threadIdx.x;
  const f16* xnb = xn + (size_t)b * 4194304;
  f16* y1b = y1 + (size_t)b * 1048576;
  int h0 = (blk >> 4) << 4, w0 = (blk & 15) << 4;
  for (int i = t; i < 2304; i += 256) {
    int co = i / 144, r = i % 144, tap = r >> 4, ci = r & 15;
    wpk[i] = (f16)pw[co * 144 + ci * 9 + tap];
  }
  if (t < 16) pbs[t] = pb[t];
  for (int i = 0; i < 3; ++i) {
    int u = i * 256 + t;
    if (u < 648) {
      int hp = u >> 1, half = u & 1;
      int hr = hp / 18, hc = hp - hr * 18;
      int h = h0 - 1 + hr, w = w0 - 1 + hc;
      f16x8 v = {0, 0, 0, 0, 0, 0, 0, 0};
      if ((unsigned)h < 256u && (unsigned)w < 256u)
        v = *(const f16x8*)(xnb + ((((size_t)h << 8)) + w) * 64 + half * 8);
      *(f16x8*)(halo + hr * 640 + ((hc * 32 + half * 16) ^ ((hr & 7) << 4))) = v;
    }
  }
  __syncthreads();
  int rl = t >> 4, cl = t & 15;
  float acc[16];
#pragma unroll
  for (int co = 0; co < 16; ++co) acc[co] = pbs[co];
#pragma unroll
  for (int ty = 0; ty < 3; ++ty)
#pragma unroll
    for (int tx = 0; tx < 3; ++tx) {
      int hr = rl + ty, hc = cl + tx, tap = ty * 3 + tx;
      f16x8 ld0 = *(const f16x8*)(halo + hr * 640 + ((hc * 32) ^ ((hr & 7) << 4)));
      f16x8 ld1 = *(const f16x8*)(halo + hr * 640 + ((hc * 32 + 16) ^ ((hr & 7) << 4)));
#pragma unroll
      for (int co = 0; co < 16; ++co) {
#pragma unroll
        for (int p = 0; p < 4; ++p) {
          f16x2 xp = {ld0[2 * p], ld0[2 * p + 1]};
          f16x2 wp = *(const f16x2*)&wpk[co * 144 + tap * 16 + 2 * p];
          acc[co] = dot2f(xp, wp, acc[co]);
        }
#pragma unroll
        for (int p = 0; p < 4; ++p) {
          f16x2 xp = {ld1[2 * p], ld1[2 * p + 1]};
          f16x2 wp = *(const f16x2*)&wpk[co * 144 + tap * 16 + 8 + 2 * p];
          acc[co] = dot2f(xp, wp, acc[co]);
        }
      }
    }
  size_t px = (((size_t)(h0 + rl)) << 8) + w0 + cl;
  f16x8 o0, o1;
#pragma unroll
  for (int j = 0; j < 8; ++j) { o0[j] = (f16)acc[j]; o1[j] = (f16)acc[8 + j]; }
  *(f16x8*)(y1b + px * 16) = o0;
  *(f16x8*)(y1b + px * 16 + 8) = o1;
}

// ---------------------------------------------------------------------------
// Branch-1 body (round-11 numerics).  smem: As@0, Es@16384.
// ---------------------------------------------------------------------------
__device__ __forceinline__ void b1_body(
    char* smem, int sub, int b, const f16* __restrict__ xn,
    const f16* __restrict__ W0h, const float* __restrict__ b0,
    const f16* __restrict__ W2h, const float* __restrict__ b2,
    f16* __restrict__ u1d, f16* __restrict__ u1w) {
  f16* As = (f16*)smem;
  f16* Es = (f16*)(smem + 16384);
  int t = threadIdx.x;
  const f16* xnb = xn + (size_t)b * 4194304;
  f16* u1b = (b < 3) ? (u1d + (size_t)b * 4194304) : u1w;
  int px0 = sub << 7;
#pragma unroll
  for (int i = 0; i < 4; ++i) {
    int u = i * 256 + t, row = u >> 3, cb = (u & 7) << 4;
    f16x8 v = *(const f16x8*)(xnb + (size_t)(px0 + row) * 64 + (cb >> 1));
    *(f16x8*)((char*)As + row * 128 + (cb ^ ((row & 7) << 4))) = v;
  }
  __syncthreads();
  int l = t & 63, wv = t >> 6, lm = l & 15, kg = l >> 4;
  f32x4 uacc[2][4];
#pragma unroll
  for (int a = 0; a < 2; ++a)
#pragma unroll
    for (int n = 0; n < 4; ++n) uacc[a][n] = (f32x4){0.f, 0.f, 0.f, 0.f};
  for (int cc = 0; cc < 4; ++cc) {
    f32x4 eacc[2][4];
#pragma unroll
    for (int a = 0; a < 2; ++a)
#pragma unroll
      for (int n = 0; n < 4; ++n) eacc[a][n] = (f32x4){0.f, 0.f, 0.f, 0.f};
#pragma unroll
    for (int kk = 0; kk < 2; ++kk) {
      int kb = kk * 64 + kg * 16;
      f16x8 af[2];
#pragma unroll
      for (int mt = 0; mt < 2; ++mt) {
        int row = wv * 32 + mt * 16 + lm;
        af[mt] = *(const f16x8*)((char*)As + row * 128 + (kb ^ ((row & 7) << 4)));
      }
      f16x8 bf[4];
#pragma unroll
      for (int nt = 0; nt < 4; ++nt) {
        int co = cc * 64 + nt * 16 + lm;
        bf[nt] = *(const f16x8*)(W0h + (size_t)co * 64 + kk * 32 + kg * 8);
      }
#pragma unroll
      for (int mt = 0; mt < 2; ++mt)
#pragma unroll
        for (int nt = 0; nt < 4; ++nt)
          eacc[mt][nt] = __builtin_amdgcn_mfma_f32_16x16x32_f16(bf[nt], af[mt], eacc[mt][nt], 0, 0, 0);
    }
    if (cc) __syncthreads();
#pragma unroll
    for (int mt = 0; mt < 2; ++mt) {
      int row = wv * 32 + mt * 16 + lm;
#pragma unroll
      for (int nt = 0; nt < 4; ++nt) {
        int c0 = nt * 16 + kg * 4;
        float4 bz4 = *(const float4*)&b0[cc * 64 + c0];
        f16x2 lo = gelu_pk(cvtpk(eacc[mt][nt][0] + bz4.x, eacc[mt][nt][1] + bz4.y));
        f16x2 hi = gelu_pk(cvtpk(eacc[mt][nt][2] + bz4.z, eacc[mt][nt][3] + bz4.w));
        f16x4 pk = {lo[0], lo[1], hi[0], hi[1]};
        *(f16x4*)((char*)Es + row * 128 + ((c0 * 2) ^ ((row & 7) << 4))) = pk;
      }
    }
    __syncthreads();
#pragma unroll
    for (int kk = 0; kk < 2; ++kk) {
      int kb = kk * 64 + kg * 16;
      f16x8 af[2];
#pragma unroll
      for (int mt = 0; mt < 2; ++mt) {
        int row = wv * 32 + mt * 16 + lm;
        af[mt] = *(const f16x8*)((char*)Es + row * 128 + (kb ^ ((row & 7) << 4)));
      }
      f16x8 bf[4];
#pragma unroll
      for (int nt = 0; nt < 4; ++nt) {
        int co = nt * 16 + lm;
        bf[nt] = *(const f16x8*)(W2h + (size_t)co * 256 + cc * 64 + kk * 32 + kg * 8);
      }
#pragma unroll
      for (int mt = 0; mt < 2; ++mt)
#pragma unroll
        for (int nt = 0; nt < 4; ++nt)
          uacc[mt][nt] = __builtin_amdgcn_mfma_f32_16x16x32_f16(bf[nt], af[mt], uacc[mt][nt], 0, 0, 0);
    }
    __syncthreads();
  }
#pragma unroll
  for (int mt = 0; mt < 2; ++mt) {
    int row = wv * 32 + mt * 16 + lm;
#pragma unroll
    for (int nt = 0; nt < 4; ++nt) {
      int c0 = nt * 16 + kg * 4;
      float4 bz4 = *(const float4*)&b2[c0];
      f16x2 lo = cvtpk(uacc[mt][nt][0] + bz4.x, uacc[mt][nt][1] + bz4.y);
      f16x2 hi = cvtpk(uacc[mt][nt][2] + bz4.z, uacc[mt][nt][3] + bz4.w);
      f16x4 pk = {lo[0], lo[1], hi[0], hi[1]};
      *(f16x4*)((char*)Es + row * 128 + ((c0 * 2) ^ ((row & 7) << 4))) = pk;
    }
  }
  __syncthreads();
  int co = t >> 2, q = t & 3;
  f16x8 o[4];
#pragma unroll
  for (int i = 0; i < 32; ++i) {
    int m = q * 32 + i;
    o[i >> 3][i & 7] =
        *(const f16*)((char*)Es + m * 128 + ((co * 2) ^ ((m & 7) << 4)));
  }
  f16* up = u1b + ((size_t)co << 16) + px0 + q * 32;
#pragma unroll
  for (int ss = 0; ss < 4; ++ss) *(f16x8*)(up + ss * 8) = o[ss];
}

// ---------------------------------------------------------------------------
// b1+pconv launch: x<2048 -> b1 (b=x>>9, sub=x&511); else pconv
// (u=x-2048, b=u>>8, blk=u&255).  LDS 32KB (pconv uses 16.2KB of it).
// ---------------------------------------------------------------------------
__global__ void __launch_bounds__(256) b1pc_kernel(
    const f16* __restrict__ xn, const f16* __restrict__ W0h,
    const float* __restrict__ b0, const f16* __restrict__ W2h,
    const float* __restrict__ b2, f16* __restrict__ u1d,
    f16* __restrict__ u1w, const float* __restrict__ pw,
    const float* __restrict__ pb, f16* __restrict__ y1) {
  __shared__ __align__(16) char smem[32768];
  int xb = blockIdx.x;
  if (xb < 2048)
    b1_body(smem, xb & 511, xb >> 9, xn, W0h, b0, W2h, b2, u1d, u1w);
  else {
    int u = xb - 2048;
    pconv_body(smem, u & 255, u >> 8, xn, pw, pb, y1);
  }
}

// ---------------------------------------------------------------------------
// b2 expand helper: eacc = xn-halo . W1 chunk (12 m-tiles x 2 n-tiles).
// ---------------------------------------------------------------------------
__device__ __forceinline__ void b2_expand(
    const char* xin, const f16* __restrict__ W1h, int ce0, int wv, int lm,
    int kg, f32x4 (&eacc)[3][2]) {
#pragma unroll
  for (int a = 0; a < 3; ++a)
#pragma unroll
    for (int n = 0; n < 2; ++n) eacc[a][n] = (f32x4){0.f, 0.f, 0.f, 0.f};
#pragma unroll
  for (int kk = 0; kk < 2; ++kk) {
    int kb = kk * 64 + kg * 16;
    f16x8 af[3];
#pragma unroll
    for (int mtl = 0; mtl < 3; ++mtl) {
      int row = (mtl * 4 + wv) * 16 + lm;
      af[mtl] = *(const f16x8*)(xin + row * 128 + (kb ^ ((row & 7) << 4)));
    }
    f16x8 bf[2];
#pragma unroll
    for (int nt = 0; nt < 2; ++nt) {
      int ce = ce0 + nt * 16 + lm;
      bf[nt] = *(const f16x8*)(W1h + (size_t)ce * 64 + kk * 32 + kg * 8);
    }
#pragma unroll
    for (int mtl = 0; mtl < 3; ++mtl)
#pragma unroll
      for (int nt = 0; nt < 2; ++nt)
        eacc[mtl][nt] = __builtin_amdgcn_mfma_f32_16x16x32_f16(bf[nt], af[mtl], eacc[mtl][nt], 0, 0, 0);
  }
}

// ---------------------------------------------------------------------------
// Fused branch 2 (round-11 numerics, expand PIPELINED one sub ahead so its
// MFMAs overlap dw's ds_read/VALU).  grid (512, 4).
// ---------------------------------------------------------------------------
__global__ void __launch_bounds__(256) b2_kernel(
    const f16* __restrict__ xn, const f16* __restrict__ y1,
    const f16* __restrict__ W1h, const float* __restrict__ b1v,
    const f16* __restrict__ W4h, const float* __restrict__ b4,
    const f16* __restrict__ w3pk, const f16* __restrict__ b3pk,
    f16* __restrict__ u2) {
  __shared__ __align__(16) f16 xin[12288];  // 192 rows x 64 ci, 128B rows
  __shared__ __align__(16) f16 Es[6144];    // 192 rows x 32 ce, 64B rows
  int t = threadIdx.x, blk = blockIdx.x, b = blockIdx.y;
  const f16* xnb = xn + (size_t)b * 4194304;
  const f16* y1b = y1 + (size_t)b * 1048576;
  f16* u2b = u2 + (size_t)b * 4194304;
  int h0 = (blk >> 4) << 3, w0 = (blk & 15) << 4;
#pragma unroll
  for (int i = 0; i < 6; ++i) {
    int u = i * 256 + t;                 // 0..1535 = 192 rows x 8 parts
    int hp = u >> 3, part = u & 7;
    f16x8 v = {0, 0, 0, 0, 0, 0, 0, 0};
    if (hp < 180) {
      int hr = hp / 18, hc = hp - hr * 18;
      int h = h0 - 1 + hr, w = w0 - 1 + hc;
      if ((unsigned)h < 256u && (unsigned)w < 256u) {
        size_t px = ((size_t)h << 8) + w;
        v = (part < 2) ? *(const f16x8*)(y1b + px * 16 + part * 8)
                       : *(const f16x8*)(xnb + px * 64 + part * 8);
      }
    }
    *(f16x8*)((char*)xin + hp * 128 + ((part * 16) ^ ((hp & 7) << 4))) = v;
  }
  __syncthreads();
  int l = t & 63, wv = t >> 6, lm = l & 15, kg = l >> 4;
  f32x4 uacc[2][4];
#pragma unroll
  for (int a = 0; a < 2; ++a)
#pragma unroll
    for (int n = 0; n < 4; ++n) uacc[a][n] = (f32x4){0.f, 0.f, 0.f, 0.f};
  f32x4 eacc[3][2];
  b2_expand((const char*)xin, W1h, 0, wv, lm, kg, eacc);
  for (int it = 0; it < 8; ++it) {
    int ce0 = it * 32;
    if (it) __syncthreads();   // prior dw reads of Es complete
    // spill eacc -> Es (gelu, packed)
#pragma unroll
    for (int mtl = 0; mtl < 3; ++mtl) {
      int row = (mtl * 4 + wv) * 16 + lm;
#pragma unroll
      for (int nt = 0; nt < 2; ++nt) {
        int cL = nt * 16 + kg * 4;
        float4 bz4 = *(const float4*)&b1v[ce0 + cL];
        f16x2 lo = gelu_pk(cvtpk(eacc[mtl][nt][0] + bz4.x, eacc[mtl][nt][1] + bz4.y));
        f16x2 hi = gelu_pk(cvtpk(eacc[mtl][nt][2] + bz4.z, eacc[mtl][nt][3] + bz4.w));
        f16x4 pk = {lo[0], lo[1], hi[0], hi[1]};
        *(f16x4*)((char*)Es + row * 64 + ((cL * 2) ^ (((row >> 1) & 3) << 4))) = pk;
      }
    }
    __syncthreads();           // Es visible to all
    // pipelined: next sub's expand (MFMA pipe) overlaps dw (VALU/LDS)
    if (it < 7) b2_expand((const char*)xin, W1h, ce0 + 32, wv, lm, kg, eacc);
    // dw 3x3 + gelu: thread computes ITS contract B-fragment directly
    int g9 = (ce0 + kg * 8) >> 3;
    f16x8 wv9[9];
#pragma unroll
    for (int tap = 0; tap < 9; ++tap)
      wv9[tap] = *(const f16x8*)(w3pk + g9 * 72 + tap * 8);
    f16x8 bias8 = *(const f16x8*)(b3pk + ce0 + kg * 8);
    f16x8 af2[2];
#pragma unroll
    for (int mt = 0; mt < 2; ++mt) {
      int px = wv * 32 + mt * 16 + lm;
      int rl2 = px >> 4, cl2 = px & 15;
      f16x8 a8 = bias8;
#pragma unroll
      for (int ty = 0; ty < 3; ++ty)
#pragma unroll
        for (int tx = 0; tx < 3; ++tx) {
          int hp = (rl2 + ty) * 18 + (cl2 + tx);
          f16x8 xv = *(const f16x8*)((char*)Es + hp * 64 + ((kg * 16) ^ (((hp >> 1) & 3) << 4)));
          a8 += xv * wv9[ty * 3 + tx];
        }
#pragma unroll
      for (int j2 = 0; j2 < 4; ++j2) {
        f16x2 g = gelu_pk((f16x2){a8[2 * j2], a8[2 * j2 + 1]});
        af2[mt][2 * j2] = g[0];
        af2[mt][2 * j2 + 1] = g[1];
      }
    }
    f16x8 bf2[4];
#pragma unroll
    for (int nt = 0; nt < 4; ++nt) {
      int co = nt * 16 + lm;
      bf2[nt] = *(const f16x8*)(W4h + (size_t)co * 256 + ce0 + kg * 8);
    }
#pragma unroll
    for (int mt = 0; mt < 2; ++mt)
#pragma unroll
      for (int nt = 0; nt < 4; ++nt)
        uacc[mt][nt] = __builtin_amdgcn_mfma_f32_16x16x32_f16(bf2[nt], af2[mt], uacc[mt][nt], 0, 0, 0);
  }
  __syncthreads();   // all xin reads done before epilogue reuse
#pragma unroll
  for (int mt = 0; mt < 2; ++mt) {
    int m = wv * 32 + mt * 16 + lm;
#pragma unroll
    for (int nt = 0; nt < 4; ++nt) {
      int c0 = nt * 16 + kg * 4;
      float4 bz4 = *(const float4*)&b4[c0];
      f16x2 lo = cvtpk(uacc[mt][nt][0] + bz4.x, uacc[mt][nt][1] + bz4.y);
      f16x2 hi = cvtpk(uacc[mt][nt][2] + bz4.z, uacc[mt][nt][3] + bz4.w);
      f16x4 pk = {lo[0], lo[1], hi[0], hi[1]};
      *(f16x4*)((char*)xin + m * 128 + ((c0 * 2) ^ ((m & 7) << 4))) = pk;
    }
  }
  __syncthreads();
  int co = t >> 2, q = t & 3;
  f16x8 o[4];
#pragma unroll
  for (int i = 0; i < 32; ++i) {
    int m = q * 32 + i;
    o[i >> 3][i & 7] =
        *(const f16*)((char*)xin + m * 128 + ((co * 2) ^ ((m & 7) << 4)));
  }
  f16* up = u2b + ((size_t)co << 16) + (size_t)(h0 + 2 * q) * 256 + w0;
  *(f16x8*)(up) = o[0];
  *(f16x8*)(up + 8) = o[1];
  *(f16x8*)(up + 256) = o[2];
  *(f16x8*)(up + 256 + 8) = o[3];
}

// ---------------------------------------------------------------------------
// out(b) = circconv8x8(u1,k1) + circconv8x8(u2,k2).  b = base + blockIdx.y.
// grid (1024, nb).
// ---------------------------------------------------------------------------
__global__ void __launch_bounds__(256) fftmix_kernel(
    const f16* __restrict__ u1d, const f16* __restrict__ u1w,
    const f16* __restrict__ u2, const float* __restrict__ kap1,
    const float* __restrict__ kap2, float* __restrict__ out, int base) {
  int blk = blockIdx.x;
  int b = base + blockIdx.y;
  int c = blk >> 4, part = blk & 15;
  int t = threadIdx.x;
  int l = t & 63, wv = (t >> 6) & 3;
  int s = l >> 3, tq = l & 7;
  __shared__ unsigned int kls[64];
  if (t < 64) {
    f16 k1 = (f16)kap1[(c << 6) + t];
    f16 k2 = (f16)kap2[(c << 6) + t];
    kls[t] = (unsigned int)__builtin_bit_cast(unsigned short, k1) |
             ((unsigned int)__builtin_bit_cast(unsigned short, k2) << 16);
  }
  __syncthreads();
  unsigned int kp[64];
#pragma unroll
  for (int j = 0; j < 64; ++j) {
    int idx = (((s - (j >> 3)) & 7) << 3) | ((tq - (j & 7)) & 7);
    kp[j] = kls[idx];
  }
  const f16* u1 = (b < 3) ? (u1d + (size_t)b * 4194304) : u1w;
  const f16* u2b = u2 + (size_t)b * 4194304;
  size_t cb = ((size_t)c) << 16;
  size_t obase = ((size_t)(b * 64 + c)) << 16;
  int win0 = part * 64 + wv * 16;
  for (int it = 0; it < 16; ++it) {
    int win = win0 + it;
    int wh = win >> 5, ww = win & 31;
    size_t pix = (size_t)((wh * 8 + s) << 8) + ww * 8 + tq;
    unsigned int pk =
        (unsigned int)__builtin_bit_cast(unsigned short, u1[cb + pix]) |
        ((unsigned int)__builtin_bit_cast(unsigned short, u2b[cb + pix]) << 16);
    float ac0 = 0.f, ac1 = 0.f, ac2 = 0.f, ac3 = 0.f;
#pragma unroll
    for (int j = 0; j < 64; j += 4) {
      unsigned int v0 = (unsigned int)__builtin_amdgcn_readlane((int)pk, j);
      unsigned int v1 = (unsigned int)__builtin_amdgcn_readlane((int)pk, j + 1);
      unsigned int v2 = (unsigned int)__builtin_amdgcn_readlane((int)pk, j + 2);
      unsigned int v3 = (unsigned int)__builtin_amdgcn_readlane((int)pk, j + 3);
      ac0 = dot2f(__builtin_bit_cast(f16x2, v0), __builtin_bit_cast(f16x2, kp[j]), ac0);
      ac1 = dot2f(__builtin_bit_cast(f16x2, v1), __builtin_bit_cast(f16x2, kp[j + 1]), ac1);
      ac2 = dot2f(__builtin_bit_cast(f16x2, v2), __builtin_bit_cast(f16x2, kp[j + 2]), ac2);
      ac3 = dot2f(__builtin_bit_cast(f16x2, v3), __builtin_bit_cast(f16x2, kp[j + 3]), ac3);
    }
    out[obase + pix] = (ac0 + ac1) + (ac2 + ac3);
  }
}

// ---------------------------------------------------------------------------
__global__ void diag_kernel(float* __restrict__ out, float code, int n) {
  int i = blockIdx.x * 256 + threadIdx.x;
  for (int p = i; p < n; p += 256 * 4096) out[p] = (p == 0) ? code : 0.f;
}

// ---------------------------------------------------------------------------
extern "C" void kernel_launch(void* const* d_in, const int* in_sizes, int n_in,
                              void* d_out, int out_size, void* d_ws,
                              size_t ws_size, hipStream_t stream) {
  const float* x       = (const float*)d_in[0];
  const float* ln_w    = (const float*)d_in[1];
  const float* ln_b    = (const float*)d_in[2];
  const float* pconv_w = (const float*)d_in[3];
  const float* pconv_b = (const float*)d_in[4];
  const float* w0      = (const float*)d_in[5];
  const float* b0      = (const float*)d_in[6];
  const float* w1      = (const float*)d_in[7];
  const float* b1      = (const float*)d_in[8];
  const float* w2      = (const float*)d_in[9];
  const float* b2      = (const float*)d_in[10];
  const float* w3      = (const float*)d_in[11];
  const float* b3      = (const float*)d_in[12];
  const float* w4      = (const float*)d_in[13];
  const float* b4      = (const float*)d_in[14];
  const float* fftw1   = (const float*)d_in[15];
  const float* fftw2   = (const float*)d_in[16];

  const size_t OFF_KAP1 = 0;                        // f32 [64][64] = 16 KB
  const size_t OFF_KAP2 = 16384;
  const size_t OFF_W0H  = 32768;                    // 32 KB each
  const size_t OFF_W1H  = 65536;
  const size_t OFF_W2H  = 98304;
  const size_t OFF_W4H  = 131072;
  const size_t OFF_W3PK = 163840;                   // 4608 B
  const size_t OFF_B3PK = 168448;                   // 512 B
  const size_t OFF_Y1   = 168960;                   // f16 4 x [65536][16] = 8 MB
  const size_t OFF_U2   = OFF_Y1 + 8388608ull;      // f16 4 x [64][65536] = 32 MB
  const size_t OFF_U13  = OFF_U2 + 33554432ull;     // f16 [64][65536] = 8 MB (b=3)
  const size_t WS_NEED  = OFF_U13 + 8388608ull;     // 50,500,608 B (proven fits)

  float* outF = (float*)d_out;
  if (ws_size < WS_NEED) {
    diag_kernel<<<4096, 256, 0, stream>>>(outF, 1000.0f + (float)(ws_size >> 20), 16777216);
    return;
  }
  char* ws = (char*)d_ws;
  float* kap1 = (float*)(ws + OFF_KAP1);
  float* kap2 = (float*)(ws + OFF_KAP2);
  f16* W0h  = (f16*)(ws + OFF_W0H);
  f16* W1h  = (f16*)(ws + OFF_W1H);
  f16* W2h  = (f16*)(ws + OFF_W2H);
  f16* W4h  = (f16*)(ws + OFF_W4H);
  f16* w3pk = (f16*)(ws + OFF_W3PK);
  f16* b3pk = (f16*)(ws + OFF_B3PK);
  f16* Y1   = (f16*)(ws + OFF_Y1);
  f16* U2   = (f16*)(ws + OFF_U2);
  f16* U13  = (f16*)(ws + OFF_U13);

  // d_out overlay: xn = f16[0:32MB); u1(b<3) = f16[32MB + 8MB*b)
  f16* XN  = (f16*)d_out;
  f16* U1D = (f16*)d_out + 16777216;

  lnpre_kernel<<<1322, 256, 0, stream>>>(x, ln_w, ln_b, XN,
                                         w0, w1, w2, w4, w3, b3, fftw1, fftw2,
                                         W0h, W1h, W2h, W4h, w3pk, b3pk,
                                         kap1, kap2);
  b1pc_kernel<<<3072, 256, 0, stream>>>(XN, W0h, b0, W2h, b2, U1D, U13,
                                        pconv_w, pconv_b, Y1);
  b2_kernel<<<dim3(512, 4), 256, 0, stream>>>(XN, Y1, W1h, b1, W4h, b4,
                                              w3pk, b3pk, U2);
  fftmix_kernel<<<dim3(1024, 2), 256, 0, stream>>>(U1D, U13, U2, kap1, kap2, outF, 0);
  fftmix_kernel<<<dim3(1024, 1), 256, 0, stream>>>(U1D, U13, U2, kap1, kap2, outF, 2);
  fftmix_kernel<<<dim3(1024, 1), 256, 0, stream>>>(U1D, U13, U2, kap1, kap2, outF, 3);
}

// Round 14
// 328.927 us; speedup vs baseline: 1.1449x; 1.0217x over previous
//
#include <hip/hip_runtime.h>

// Problem: B=4, C=64, H=W=256, D=16, C4=256, P=8.  HW=65536.
// xn (NHWC f16, 32MB) in d_out[0:32MB); u1 b=0..2 in d_out[32MB+8MB*b);
// u1(3), y1, u2 in ws.  fftmix batches {0,1},{2},{3} in order (overlay).
// Round 14: expand A-operands are ce-invariant -> hoisted to REGISTERS
// (loaded once from global; bytes identical to the old LDS reads).  xin/As
// buffers deleted: b2 LDS 36.9->12.3KB, b1 32.7->16.4KB.  b2 epilogue
// re-staged through Es in two 64-px chunks.

typedef _Float16 f16;
typedef _Float16 f16x2 __attribute__((ext_vector_type(2)));
typedef _Float16 f16x4 __attribute__((ext_vector_type(4)));
typedef _Float16 f16x8 __attribute__((ext_vector_type(8)));
typedef float f32x4 __attribute__((ext_vector_type(4)));

__device__ __forceinline__ float dot2f(f16x2 a, f16x2 b, float c) {
#if __has_builtin(__builtin_amdgcn_fdot2)
  return __builtin_amdgcn_fdot2(a, b, c, false);
#else
  return c + (float)a.x * (float)b.x + (float)a.y * (float)b.y;
#endif
}

// Packed-f16 tanh-form GELU: x * sigmoid(1.5958x + 0.07136x^3).
__device__ __forceinline__ f16x2 gelu_pk(f16x2 x) {
  const f16x2 c1 = {(f16)1.5957691f, (f16)1.5957691f};
  const f16x2 c3 = {(f16)0.0713548f, (f16)0.0713548f};
  const f16x2 cl = {(f16)-1.4426950f, (f16)-1.4426950f};
  f16x2 x2 = x * x;
  f16x2 u = x * (c1 + c3 * x2);
  f16x2 a = cl * u;
  f16 t0, t1;
#if __has_builtin(__builtin_amdgcn_exp2h)
  t0 = __builtin_amdgcn_exp2h(a[0]);
  t1 = __builtin_amdgcn_exp2h(a[1]);
#else
  t0 = (f16)exp2f((float)a[0]);
  t1 = (f16)exp2f((float)a[1]);
#endif
  f16 d0 = (f16)1.0f + t0, d1 = (f16)1.0f + t1;
  f16 r0, r1;
#if __has_builtin(__builtin_amdgcn_rcph)
  r0 = __builtin_amdgcn_rcph(d0);
  r1 = __builtin_amdgcn_rcph(d1);
#else
  r0 = (f16)(1.0f / (float)d0);
  r1 = (f16)(1.0f / (float)d1);
#endif
  f16x2 r = {r0, r1};
  return x * r;
}

__device__ __forceinline__ f16x2 cvtpk(float a, float b) {
  return __builtin_bit_cast(f16x2, __builtin_amdgcn_cvt_pkrtz(a, b));
}

// ---------------------------------------------------------------------------
// ln+preconv launch.  Blocks 0..1023: LayerNorm.  1024..1289: weight conv.
// 1290..1321: kappa (4 units each).
// ---------------------------------------------------------------------------
__global__ void __launch_bounds__(256) lnpre_kernel(
    const float* __restrict__ x, const float* __restrict__ lnw,
    const float* __restrict__ lnb, f16* __restrict__ xn,
    const float* __restrict__ w0, const float* __restrict__ w1,
    const float* __restrict__ w2, const float* __restrict__ w4,
    const float* __restrict__ w3, const float* __restrict__ b3,
    const float* __restrict__ fw1, const float* __restrict__ fw2,
    f16* __restrict__ W0h, f16* __restrict__ W1h,
    f16* __restrict__ W2h, f16* __restrict__ W4h,
    f16* __restrict__ w3pk, f16* __restrict__ b3pk,
    float* __restrict__ kap1, float* __restrict__ kap2) {
  __shared__ float Wt[4][64];
  __shared__ float ct[8];
  int blk = blockIdx.x, t = threadIdx.x;
  if (blk < 1024) {
    int b = blk >> 8;
    int px = (blk & 255) * 256 + t;
    const float* xp = x + ((size_t)b << 22) + px;
    float v[64];
    float s = 0.f;
#pragma unroll
    for (int c = 0; c < 64; ++c) { v[c] = xp[(size_t)c << 16]; s += v[c]; }
    float mu = s * (1.f / 64.f), s2 = 0.f;
#pragma unroll
    for (int c = 0; c < 64; ++c) { float d = v[c] - mu; s2 += d * d; }
    float rstd = rsqrtf(s2 * (1.f / 64.f) + 1e-6f);
    f16* op = xn + (size_t)b * 4194304 + (size_t)px * 64;
#pragma unroll
    for (int g = 0; g < 8; ++g) {
      f16x8 pk;
#pragma unroll
      for (int j = 0; j < 8; ++j) {
        int c = g * 8 + j;
        pk[j] = (f16)((v[c] - mu) * rstd * lnw[c] + lnb[c]);
      }
      *(f16x8*)(op + g * 8) = pk;
    }
    return;
  }
  if (blk < 1290) {
    int i = (blk - 1024) * 256 + t;
    if (i < 16384) W0h[i] = (f16)w0[i];
    else if (i < 32768) W1h[i - 16384] = (f16)w1[i - 16384];
    else if (i < 49152) W2h[i - 32768] = (f16)w2[i - 32768];
    else if (i < 65536) W4h[i - 49152] = (f16)w4[i - 49152];
    else if (i < 67840) {
      int j = i - 65536;               // [g][tap][k]: value = w3[(g*8+k)*9+tap]
      int g = j / 72, r = j % 72, tap = r >> 3, k = r & 7;
      w3pk[j] = (f16)w3[(g * 8 + k) * 9 + tap];
    } else if (i < 68096) {
      int k = i - 67840;
      b3pk[k] = (f16)b3[k];
    }
    return;
  }
  int sub = t >> 6, lane = t & 63;
  int unit = (blk - 1290) * 4 + sub;   // 0..127
  int which = unit >> 6, c = unit & 63;
  const float* fw = which ? fw2 : fw1;
  float* kap = which ? kap2 : kap1;
  int a = lane >> 3, bb = lane & 7;
  if (t == 0) {
    const float r2 = 0.70710678118654752440f;
    ct[0] = 1.f; ct[1] = r2; ct[2] = 0.f; ct[3] = -r2;
    ct[4] = -1.f; ct[5] = -r2; ct[6] = 0.f; ct[7] = r2;
  }
  Wt[sub][lane] = (bb <= 4) ? fw[c * 40 + a * 5 + bb]
                            : fw[c * 40 + ((8 - a) & 7) * 5 + (8 - bb)];
  __syncthreads();
  float acc = 0.f;
  for (int u = 0; u < 8; ++u)
    for (int v = 0; v < 8; ++v)
      acc += Wt[sub][u * 8 + v] * ct[(u * a + v * bb) & 7];
  kap[c * 64 + lane] = acc * 0.015625f;
}

// ---------------------------------------------------------------------------
// pconv body (3x3 dense conv 16ci->16co on xn c<16 -> y1 NHWC f16).
// Uses 16192 B of smem.
// ---------------------------------------------------------------------------
__device__ __forceinline__ void pconv_body(
    char* smem, int blk, int b, const f16* __restrict__ xn,
    const float* __restrict__ pw, const float* __restrict__ pb,
    f16* __restrict__ y1) {
  char* halo = smem;                          // 18 * 640 = 11520
  f16* wpk = (f16*)(smem + 11520);            // 2304 f16 = 4608
  float* pbs = (float*)(smem + 16128);        // 64
  int t = threadIdx.x;
  const f16* xnb = xn + (size_t)b * 4194304;
  f16* y1b = y1 + (size_t)b * 1048576;
  int h0 = (blk >> 4) << 4, w0 = (blk & 15) << 4;
  for (int i = t; i < 2304; i += 256) {
    int co = i / 144, r = i % 144, tap = r >> 4, ci = r & 15;
    wpk[i] = (f16)pw[co * 144 + ci * 9 + tap];
  }
  if (t < 16) pbs[t] = pb[t];
  for (int i = 0; i < 3; ++i) {
    int u = i * 256 + t;
    if (u < 648) {
      int hp = u >> 1, half = u & 1;
      int hr = hp / 18, hc = hp - hr * 18;
      int h = h0 - 1 + hr, w = w0 - 1 + hc;
      f16x8 v = {0, 0, 0, 0, 0, 0, 0, 0};
      if ((unsigned)h < 256u && (unsigned)w < 256u)
        v = *(const f16x8*)(xnb + ((((size_t)h << 8)) + w) * 64 + half * 8);
      *(f16x8*)(halo + hr * 640 + ((hc * 32 + half * 16) ^ ((hr & 7) << 4))) = v;
    }
  }
  __syncthreads();
  int rl = t >> 4, cl = t & 15;
  float acc[16];
#pragma unroll
  for (int co = 0; co < 16; ++co) acc[co] = pbs[co];
#pragma unroll
  for (int ty = 0; ty < 3; ++ty)
#pragma unroll
    for (int tx = 0; tx < 3; ++tx) {
      int hr = rl + ty, hc = cl + tx, tap = ty * 3 + tx;
      f16x8 ld0 = *(const f16x8*)(halo + hr * 640 + ((hc * 32) ^ ((hr & 7) << 4)));
      f16x8 ld1 = *(const f16x8*)(halo + hr * 640 + ((hc * 32 + 16) ^ ((hr & 7) << 4)));
#pragma unroll
      for (int co = 0; co < 16; ++co) {
#pragma unroll
        for (int p = 0; p < 4; ++p) {
          f16x2 xp = {ld0[2 * p], ld0[2 * p + 1]};
          f16x2 wp = *(const f16x2*)&wpk[co * 144 + tap * 16 + 2 * p];
          acc[co] = dot2f(xp, wp, acc[co]);
        }
#pragma unroll
        for (int p = 0; p < 4; ++p) {
          f16x2 xp = {ld1[2 * p], ld1[2 * p + 1]};
          f16x2 wp = *(const f16x2*)&wpk[co * 144 + tap * 16 + 8 + 2 * p];
          acc[co] = dot2f(xp, wp, acc[co]);
        }
      }
    }
  size_t px = (((size_t)(h0 + rl)) << 8) + w0 + cl;
  f16x8 o0, o1;
#pragma unroll
  for (int j = 0; j < 8; ++j) { o0[j] = (f16)acc[j]; o1[j] = (f16)acc[8 + j]; }
  *(f16x8*)(y1b + px * 16) = o0;
  *(f16x8*)(y1b + px * 16 + 8) = o1;
}

// ---------------------------------------------------------------------------
// Branch-1 body.  A-fragments in registers (loaded once from xn global,
// ce-invariant).  smem: Es only (16384 B).
// ---------------------------------------------------------------------------
__device__ __forceinline__ void b1_body(
    char* smem, int sub, int b, const f16* __restrict__ xn,
    const f16* __restrict__ W0h, const float* __restrict__ b0,
    const f16* __restrict__ W2h, const float* __restrict__ b2,
    f16* __restrict__ u1d, f16* __restrict__ u1w) {
  f16* Es = (f16*)smem;
  int t = threadIdx.x;
  const f16* xnb = xn + (size_t)b * 4194304;
  f16* u1b = (b < 3) ? (u1d + (size_t)b * 4194304) : u1w;
  int px0 = sub << 7;
  int l = t & 63, wv = t >> 6, lm = l & 15, kg = l >> 4;
  // A fragments: [mt][kk], ci0 = kk*32 + kg*8 (16B contiguous in NHWC xn)
  f16x8 a[2][2];
#pragma unroll
  for (int mt = 0; mt < 2; ++mt) {
    int row = wv * 32 + mt * 16 + lm;
#pragma unroll
    for (int kk = 0; kk < 2; ++kk)
      a[mt][kk] = *(const f16x8*)(xnb + (size_t)(px0 + row) * 64 + kk * 32 + kg * 8);
  }
  f32x4 uacc[2][4];
#pragma unroll
  for (int aa = 0; aa < 2; ++aa)
#pragma unroll
    for (int n = 0; n < 4; ++n) uacc[aa][n] = (f32x4){0.f, 0.f, 0.f, 0.f};
  for (int cc = 0; cc < 4; ++cc) {
    f32x4 eacc[2][4];
#pragma unroll
    for (int aa = 0; aa < 2; ++aa)
#pragma unroll
      for (int n = 0; n < 4; ++n) eacc[aa][n] = (f32x4){0.f, 0.f, 0.f, 0.f};
#pragma unroll
    for (int kk = 0; kk < 2; ++kk) {
      f16x8 bf[4];
#pragma unroll
      for (int nt = 0; nt < 4; ++nt) {
        int co = cc * 64 + nt * 16 + lm;
        bf[nt] = *(const f16x8*)(W0h + (size_t)co * 64 + kk * 32 + kg * 8);
      }
#pragma unroll
      for (int mt = 0; mt < 2; ++mt)
#pragma unroll
        for (int nt = 0; nt < 4; ++nt)
          eacc[mt][nt] = __builtin_amdgcn_mfma_f32_16x16x32_f16(bf[nt], a[mt][kk], eacc[mt][nt], 0, 0, 0);
    }
    if (cc) __syncthreads();
#pragma unroll
    for (int mt = 0; mt < 2; ++mt) {
      int row = wv * 32 + mt * 16 + lm;
#pragma unroll
      for (int nt = 0; nt < 4; ++nt) {
        int c0 = nt * 16 + kg * 4;
        float4 bz4 = *(const float4*)&b0[cc * 64 + c0];
        f16x2 lo = gelu_pk(cvtpk(eacc[mt][nt][0] + bz4.x, eacc[mt][nt][1] + bz4.y));
        f16x2 hi = gelu_pk(cvtpk(eacc[mt][nt][2] + bz4.z, eacc[mt][nt][3] + bz4.w));
        f16x4 pk = {lo[0], lo[1], hi[0], hi[1]};
        *(f16x4*)((char*)Es + row * 128 + ((c0 * 2) ^ ((row & 7) << 4))) = pk;
      }
    }
    __syncthreads();
#pragma unroll
    for (int kk = 0; kk < 2; ++kk) {
      int kb = kk * 64 + kg * 16;
      f16x8 af[2];
#pragma unroll
      for (int mt = 0; mt < 2; ++mt) {
        int row = wv * 32 + mt * 16 + lm;
        af[mt] = *(const f16x8*)((char*)Es + row * 128 + (kb ^ ((row & 7) << 4)));
      }
      f16x8 bf[4];
#pragma unroll
      for (int nt = 0; nt < 4; ++nt) {
        int co = nt * 16 + lm;
        bf[nt] = *(const f16x8*)(W2h + (size_t)co * 256 + cc * 64 + kk * 32 + kg * 8);
      }
#pragma unroll
      for (int mt = 0; mt < 2; ++mt)
#pragma unroll
        for (int nt = 0; nt < 4; ++nt)
          uacc[mt][nt] = __builtin_amdgcn_mfma_f32_16x16x32_f16(bf[nt], af[mt], uacc[mt][nt], 0, 0, 0);
    }
    __syncthreads();
  }
#pragma unroll
  for (int mt = 0; mt < 2; ++mt) {
    int row = wv * 32 + mt * 16 + lm;
#pragma unroll
    for (int nt = 0; nt < 4; ++nt) {
      int c0 = nt * 16 + kg * 4;
      float4 bz4 = *(const float4*)&b2[c0];
      f16x2 lo = cvtpk(uacc[mt][nt][0] + bz4.x, uacc[mt][nt][1] + bz4.y);
      f16x2 hi = cvtpk(uacc[mt][nt][2] + bz4.z, uacc[mt][nt][3] + bz4.w);
      f16x4 pk = {lo[0], lo[1], hi[0], hi[1]};
      *(f16x4*)((char*)Es + row * 128 + ((c0 * 2) ^ ((row & 7) << 4))) = pk;
    }
  }
  __syncthreads();
  int co = t >> 2, q = t & 3;
  f16x8 o[4];
#pragma unroll
  for (int i = 0; i < 32; ++i) {
    int m = q * 32 + i;
    o[i >> 3][i & 7] =
        *(const f16*)((char*)Es + m * 128 + ((co * 2) ^ ((m & 7) << 4)));
  }
  f16* up = u1b + ((size_t)co << 16) + px0 + q * 32;
#pragma unroll
  for (int ss = 0; ss < 4; ++ss) *(f16x8*)(up + ss * 8) = o[ss];
}

// ---------------------------------------------------------------------------
// b1+pconv launch: x<2048 -> b1; else pconv.  LDS 16384 B.
// ---------------------------------------------------------------------------
__global__ void __launch_bounds__(256) b1pc_kernel(
    const f16* __restrict__ xn, const f16* __restrict__ W0h,
    const float* __restrict__ b0, const f16* __restrict__ W2h,
    const float* __restrict__ b2, f16* __restrict__ u1d,
    f16* __restrict__ u1w, const float* __restrict__ pw,
    const float* __restrict__ pb, f16* __restrict__ y1) {
  __shared__ __align__(16) char smem[16384];
  int xb = blockIdx.x;
  if (xb < 2048)
    b1_body(smem, xb & 511, xb >> 9, xn, W0h, b0, W2h, b2, u1d, u1w);
  else {
    int u = xb - 2048;
    pconv_body(smem, u & 255, u >> 8, xn, pw, pb, y1);
  }
}

// ---------------------------------------------------------------------------
// b2 expand: eacc = A(regs) . W1 chunk (12 m-tiles x 2 n-tiles).
// ---------------------------------------------------------------------------
__device__ __forceinline__ void b2_expand(
    const f16x8 (&a0)[3], const f16x8 (&a1)[3], const f16* __restrict__ W1h,
    int ce0, int lm, int kg, f32x4 (&eacc)[3][2]) {
#pragma unroll
  for (int a = 0; a < 3; ++a)
#pragma unroll
    for (int n = 0; n < 2; ++n) eacc[a][n] = (f32x4){0.f, 0.f, 0.f, 0.f};
#pragma unroll
  for (int kk = 0; kk < 2; ++kk) {
    f16x8 bf[2];
#pragma unroll
    for (int nt = 0; nt < 2; ++nt) {
      int ce = ce0 + nt * 16 + lm;
      bf[nt] = *(const f16x8*)(W1h + (size_t)ce * 64 + kk * 32 + kg * 8);
    }
#pragma unroll
    for (int mtl = 0; mtl < 3; ++mtl) {
      f16x8 af = kk ? a1[mtl] : a0[mtl];
#pragma unroll
      for (int nt = 0; nt < 2; ++nt)
        eacc[mtl][nt] = __builtin_amdgcn_mfma_f32_16x16x32_f16(bf[nt], af, eacc[mtl][nt], 0, 0, 0);
    }
  }
}

// ---------------------------------------------------------------------------
// Fused branch 2.  A-fragments (halo) in registers, predicated once.
// LDS: Es only (12288 B).  Epilogue staged through Es in two 64-px chunks.
// grid (512, 4).
// ---------------------------------------------------------------------------
__global__ void __launch_bounds__(256) b2_kernel(
    const f16* __restrict__ xn, const f16* __restrict__ y1,
    const f16* __restrict__ W1h, const float* __restrict__ b1v,
    const f16* __restrict__ W4h, const float* __restrict__ b4,
    const f16* __restrict__ w3pk, const f16* __restrict__ b3pk,
    f16* __restrict__ u2) {
  __shared__ __align__(16) f16 Es[6144];    // 192 rows x 64 B (dw layout)
  int t = threadIdx.x, blk = blockIdx.x, b = blockIdx.y;
  const f16* xnb = xn + (size_t)b * 4194304;
  const f16* y1b = y1 + (size_t)b * 1048576;
  f16* u2b = u2 + (size_t)b * 4194304;
  int h0 = (blk >> 4) << 3, w0 = (blk & 15) << 4;
  int l = t & 63, wv = t >> 6, lm = l & 15, kg = l >> 4;
  // A fragments (ce-invariant): 3 halo rows/thread x {kk=0,1}; zero outside.
  f16x8 a0[3], a1[3];
#pragma unroll
  for (int mtl = 0; mtl < 3; ++mtl) {
    int row = (mtl * 4 + wv) * 16 + lm;
    f16x8 v0 = {0, 0, 0, 0, 0, 0, 0, 0}, v1 = v0;
    if (row < 180) {
      int hr = row / 18, hc = row - hr * 18;
      int h = h0 - 1 + hr, w = w0 - 1 + hc;
      if ((unsigned)h < 256u && (unsigned)w < 256u) {
        size_t px = ((size_t)h << 8) + w;
        v1 = *(const f16x8*)(xnb + px * 64 + 32 + kg * 8);
        v0 = (kg < 2) ? *(const f16x8*)(y1b + px * 16 + kg * 8)
                      : *(const f16x8*)(xnb + px * 64 + kg * 8);
      }
    }
    a0[mtl] = v0;
    a1[mtl] = v1;
  }
  f32x4 uacc[2][4];
#pragma unroll
  for (int a = 0; a < 2; ++a)
#pragma unroll
    for (int n = 0; n < 4; ++n) uacc[a][n] = (f32x4){0.f, 0.f, 0.f, 0.f};
  f32x4 eacc[3][2];
  b2_expand(a0, a1, W1h, 0, lm, kg, eacc);
  for (int it = 0; it < 8; ++it) {
    int ce0 = it * 32;
    if (it) __syncthreads();   // prior dw reads of Es complete
    // spill eacc -> Es (gelu, packed)
#pragma unroll
    for (int mtl = 0; mtl < 3; ++mtl) {
      int row = (mtl * 4 + wv) * 16 + lm;
#pragma unroll
      for (int nt = 0; nt < 2; ++nt) {
        int cL = nt * 16 + kg * 4;
        float4 bz4 = *(const float4*)&b1v[ce0 + cL];
        f16x2 lo = gelu_pk(cvtpk(eacc[mtl][nt][0] + bz4.x, eacc[mtl][nt][1] + bz4.y));
        f16x2 hi = gelu_pk(cvtpk(eacc[mtl][nt][2] + bz4.z, eacc[mtl][nt][3] + bz4.w));
        f16x4 pk = {lo[0], lo[1], hi[0], hi[1]};
        *(f16x4*)((char*)Es + row * 64 + ((cL * 2) ^ (((row >> 1) & 3) << 4))) = pk;
      }
    }
    __syncthreads();           // Es visible to all
    // pipelined next-sub expand (pure MFMA + W1 global loads) overlaps dw
    if (it < 7) b2_expand(a0, a1, W1h, ce0 + 32, lm, kg, eacc);
    // dw 3x3 + gelu: thread computes ITS contract B-fragment directly
    int g9 = (ce0 + kg * 8) >> 3;
    f16x8 wv9[9];
#pragma unroll
    for (int tap = 0; tap < 9; ++tap)
      wv9[tap] = *(const f16x8*)(w3pk + g9 * 72 + tap * 8);
    f16x8 bias8 = *(const f16x8*)(b3pk + ce0 + kg * 8);
    f16x8 af2[2];
#pragma unroll
    for (int mt = 0; mt < 2; ++mt) {
      int px = wv * 32 + mt * 16 + lm;
      int rl2 = px >> 4, cl2 = px & 15;
      f16x8 a8 = bias8;
#pragma unroll
      for (int ty = 0; ty < 3; ++ty)
#pragma unroll
        for (int tx = 0; tx < 3; ++tx) {
          int hp = (rl2 + ty) * 18 + (cl2 + tx);
          f16x8 xv = *(const f16x8*)((char*)Es + hp * 64 + ((kg * 16) ^ (((hp >> 1) & 3) << 4)));
          a8 += xv * wv9[ty * 3 + tx];
        }
#pragma unroll
      for (int j2 = 0; j2 < 4; ++j2) {
        f16x2 g = gelu_pk((f16x2){a8[2 * j2], a8[2 * j2 + 1]});
        af2[mt][2 * j2] = g[0];
        af2[mt][2 * j2 + 1] = g[1];
      }
    }
    f16x8 bf2[4];
#pragma unroll
    for (int nt = 0; nt < 4; ++nt) {
      int co = nt * 16 + lm;
      bf2[nt] = *(const f16x8*)(W4h + (size_t)co * 256 + ce0 + kg * 8);
    }
#pragma unroll
    for (int mt = 0; mt < 2; ++mt)
#pragma unroll
      for (int nt = 0; nt < 4; ++nt)
        uacc[mt][nt] = __builtin_amdgcn_mfma_f32_16x16x32_f16(bf2[nt], af2[mt], uacc[mt][nt], 0, 0, 0);
  }
  // --- epilogue: two 64-px chunks through Es ([64 rows][128 B] view).
  // D[co][px]: uacc[mt][nt][r] = co (nt*16+kg*4+r) at px m = wv*32+mt*16+lm.
  __syncthreads();   // all dw reads of Es done
#pragma unroll
  for (int mt = 0; mt < 2; ++mt) {
    if (mt) __syncthreads();
    int crow = wv * 16 + lm;            // compact row: (m>>5)*16 + (m&15)
#pragma unroll
    for (int nt = 0; nt < 4; ++nt) {
      int c0 = nt * 16 + kg * 4;
      float4 bz4 = *(const float4*)&b4[c0];
      f16x2 lo = cvtpk(uacc[mt][nt][0] + bz4.x, uacc[mt][nt][1] + bz4.y);
      f16x2 hi = cvtpk(uacc[mt][nt][2] + bz4.z, uacc[mt][nt][3] + bz4.w);
      f16x4 pk = {lo[0], lo[1], hi[0], hi[1]};
      *(f16x4*)((char*)Es + crow * 128 + ((c0 * 2) ^ ((crow & 7) << 4))) = pk;
    }
    __syncthreads();
    int co = t >> 2, q = t & 3;         // px row h0 + 2q + mt, 16 px
    f16x8 o0, o1;
#pragma unroll
    for (int i = 0; i < 16; ++i) {
      int crow = q * 16 + i;
      f16 vv = *(const f16*)((char*)Es + crow * 128 + ((co * 2) ^ ((crow & 7) << 4)));
      if (i < 8) o0[i] = vv;
      else o1[i - 8] = vv;
    }
    f16* up = u2b + ((size_t)co << 16) + (size_t)(h0 + 2 * q + mt) * 256 + w0;
    *(f16x8*)(up) = o0;
    *(f16x8*)(up + 8) = o1;
  }
}

// ---------------------------------------------------------------------------
// out(b) = circconv8x8(u1,k1) + circconv8x8(u2,k2).  b = base + blockIdx.y.
// ---------------------------------------------------------------------------
__global__ void __launch_bounds__(256) fftmix_kernel(
    const f16* __restrict__ u1d, const f16* __restrict__ u1w,
    const f16* __restrict__ u2, const float* __restrict__ kap1,
    const float* __restrict__ kap2, float* __restrict__ out, int base) {
  int blk = blockIdx.x;
  int b = base + blockIdx.y;
  int c = blk >> 4, part = blk & 15;
  int t = threadIdx.x;
  int l = t & 63, wv = (t >> 6) & 3;
  int s = l >> 3, tq = l & 7;
  __shared__ unsigned int kls[64];
  if (t < 64) {
    f16 k1 = (f16)kap1[(c << 6) + t];
    f16 k2 = (f16)kap2[(c << 6) + t];
    kls[t] = (unsigned int)__builtin_bit_cast(unsigned short, k1) |
             ((unsigned int)__builtin_bit_cast(unsigned short, k2) << 16);
  }
  __syncthreads();
  unsigned int kp[64];
#pragma unroll
  for (int j = 0; j < 64; ++j) {
    int idx = (((s - (j >> 3)) & 7) << 3) | ((tq - (j & 7)) & 7);
    kp[j] = kls[idx];
  }
  const f16* u1 = (b < 3) ? (u1d + (size_t)b * 4194304) : u1w;
  const f16* u2b = u2 + (size_t)b * 4194304;
  size_t cb = ((size_t)c) << 16;
  size_t obase = ((size_t)(b * 64 + c)) << 16;
  int win0 = part * 64 + wv * 16;
  for (int it = 0; it < 16; ++it) {
    int win = win0 + it;
    int wh = win >> 5, ww = win & 31;
    size_t pix = (size_t)((wh * 8 + s) << 8) + ww * 8 + tq;
    unsigned int pk =
        (unsigned int)__builtin_bit_cast(unsigned short, u1[cb + pix]) |
        ((unsigned int)__builtin_bit_cast(unsigned short, u2b[cb + pix]) << 16);
    float ac0 = 0.f, ac1 = 0.f, ac2 = 0.f, ac3 = 0.f;
#pragma unroll
    for (int j = 0; j < 64; j += 4) {
      unsigned int v0 = (unsigned int)__builtin_amdgcn_readlane((int)pk, j);
      unsigned int v1 = (unsigned int)__builtin_amdgcn_readlane((int)pk, j + 1);
      unsigned int v2 = (unsigned int)__builtin_amdgcn_readlane((int)pk, j + 2);
      unsigned int v3 = (unsigned int)__builtin_amdgcn_readlane((int)pk, j + 3);
      ac0 = dot2f(__builtin_bit_cast(f16x2, v0), __builtin_bit_cast(f16x2, kp[j]), ac0);
      ac1 = dot2f(__builtin_bit_cast(f16x2, v1), __builtin_bit_cast(f16x2, kp[j + 1]), ac1);
      ac2 = dot2f(__builtin_bit_cast(f16x2, v2), __builtin_bit_cast(f16x2, kp[j + 2]), ac2);
      ac3 = dot2f(__builtin_bit_cast(f16x2, v3), __builtin_bit_cast(f16x2, kp[j + 3]), ac3);
    }
    out[obase + pix] = (ac0 + ac1) + (ac2 + ac3);
  }
}

// ---------------------------------------------------------------------------
__global__ void diag_kernel(float* __restrict__ out, float code, int n) {
  int i = blockIdx.x * 256 + threadIdx.x;
  for (int p = i; p < n; p += 256 * 4096) out[p] = (p == 0) ? code : 0.f;
}

// ---------------------------------------------------------------------------
extern "C" void kernel_launch(void* const* d_in, const int* in_sizes, int n_in,
                              void* d_out, int out_size, void* d_ws,
                              size_t ws_size, hipStream_t stream) {
  const float* x       = (const float*)d_in[0];
  const float* ln_w    = (const float*)d_in[1];
  const float* ln_b    = (const float*)d_in[2];
  const float* pconv_w = (const float*)d_in[3];
  const float* pconv_b = (const float*)d_in[4];
  const float* w0      = (const float*)d_in[5];
  const float* b0      = (const float*)d_in[6];
  const float* w1      = (const float*)d_in[7];
  const float* b1      = (const float*)d_in[8];
  const float* w2      = (const float*)d_in[9];
  const float* b2      = (const float*)d_in[10];
  const float* w3      = (const float*)d_in[11];
  const float* b3      = (const float*)d_in[12];
  const float* w4      = (const float*)d_in[13];
  const float* b4      = (const float*)d_in[14];
  const float* fftw1   = (const float*)d_in[15];
  const float* fftw2   = (const float*)d_in[16];

  const size_t OFF_KAP1 = 0;                        // f32 [64][64] = 16 KB
  const size_t OFF_KAP2 = 16384;
  const size_t OFF_W0H  = 32768;                    // 32 KB each
  const size_t OFF_W1H  = 65536;
  const size_t OFF_W2H  = 98304;
  const size_t OFF_W4H  = 131072;
  const size_t OFF_W3PK = 163840;                   // 4608 B
  const size_t OFF_B3PK = 168448;                   // 512 B
  const size_t OFF_Y1   = 168960;                   // f16 4 x [65536][16] = 8 MB
  const size_t OFF_U2   = OFF_Y1 + 8388608ull;      // f16 4 x [64][65536] = 32 MB
  const size_t OFF_U13  = OFF_U2 + 33554432ull;     // f16 [64][65536] = 8 MB (b=3)
  const size_t WS_NEED  = OFF_U13 + 8388608ull;     // 50,500,608 B (proven fits)

  float* outF = (float*)d_out;
  if (ws_size < WS_NEED) {
    diag_kernel<<<4096, 256, 0, stream>>>(outF, 1000.0f + (float)(ws_size >> 20), 16777216);
    return;
  }
  char* ws = (char*)d_ws;
  float* kap1 = (float*)(ws + OFF_KAP1);
  float* kap2 = (float*)(ws + OFF_KAP2);
  f16* W0h  = (f16*)(ws + OFF_W0H);
  f16* W1h  = (f16*)(ws + OFF_W1H);
  f16* W2h  = (f16*)(ws + OFF_W2H);
  f16* W4h  = (f16*)(ws + OFF_W4H);
  f16* w3pk = (f16*)(ws + OFF_W3PK);
  f16* b3pk = (f16*)(ws + OFF_B3PK);
  f16* Y1   = (f16*)(ws + OFF_Y1);
  f16* U2   = (f16*)(ws + OFF_U2);
  f16* U13  = (f16*)(ws + OFF_U13);

  // d_out overlay: xn = f16[0:32MB); u1(b<3) = f16[32MB + 8MB*b)
  f16* XN  = (f16*)d_out;
  f16* U1D = (f16*)d_out + 16777216;

  lnpre_kernel<<<1322, 256, 0, stream>>>(x, ln_w, ln_b, XN,
                                         w0, w1, w2, w4, w3, b3, fftw1, fftw2,
                                         W0h, W1h, W2h, W4h, w3pk, b3pk,
                                         kap1, kap2);
  b1pc_kernel<<<3072, 256, 0, stream>>>(XN, W0h, b0, W2h, b2, U1D, U13,
                                        pconv_w, pconv_b, Y1);
  b2_kernel<<<dim3(512, 4), 256, 0, stream>>>(XN, Y1, W1h, b1, W4h, b4,
                                              w3pk, b3pk, U2);
  fftmix_kernel<<<dim3(1024, 2), 256, 0, stream>>>(U1D, U13, U2, kap1, kap2, outF, 0);
  fftmix_kernel<<<dim3(1024, 1), 256, 0, stream>>>(U1D, U13, U2, kap1, kap2, outF, 2);
  fftmix_kernel<<<dim3(1024, 1), 256, 0, stream>>>(U1D, U13, U2, kap1, kap2, outF, 3);
}